// Round 1
// baseline (245.215 us; speedup 1.0000x reference)
//
#include <hip/hip_runtime.h>
#include <math.h>

// Problem constants (fixed shapes)
//   B=256, N=P=32, OBS=96, ACT=32, DIN=128, DOUT=128, DF1=64, DF2=32
#define BS 512                         // threads per block (8 waves)
#define VAL_SZ  (256*32*32*32)         // 8388608
#define W_OFF   VAL_SZ
#define WP_OFF  (VAL_SZ + 256*32*32)   // 8650752

// ---------------------------------------------------------------------------
// Kernel 0: precompute Mq = Wq @ Wk^T and Mp = Wqp @ Wkp^T  (each 128x128)
// scores[j,a] = q[j]·k[a] = oa[j] @ Mq @ oa[a]^T  (exact refactor, fp32)
// ---------------------------------------------------------------------------
__global__ __launch_bounds__(256) void mm_precompute(
    const float* __restrict__ Wq, const float* __restrict__ Wk,
    const float* __restrict__ Wqp, const float* __restrict__ Wkp,
    float* __restrict__ M)
{
    int gid = blockIdx.x * 256 + threadIdx.x;   // 0..32767
    int mat = gid >> 14;
    int idx = gid & 16383;
    int r = idx >> 7, c = idx & 127;
    const float* A = (mat == 0) ? Wq : Wqp;
    const float* Bm = (mat == 0) ? Wk : Wkp;
    const float4* a4 = (const float4*)(A + r * 128);
    const float4* b4 = (const float4*)(Bm + c * 128);
    float acc = 0.f;
#pragma unroll
    for (int t = 0; t < 32; ++t) {
        float4 x = a4[t], y = b4[t];
        acc = fmaf(x.x, y.x, acc);
        acc = fmaf(x.y, y.y, acc);
        acc = fmaf(x.z, y.z, acc);
        acc = fmaf(x.w, y.w, acc);
    }
    M[gid] = acc;
}

// ---------------------------------------------------------------------------
// helpers: 32x128 @ 128x128 GEMM, each thread produces 2 float4 groups.
// group gi = tid + g*512 -> n = gi>>5 (row), d4 = gi&31 (float4 col).
// LDS row reads are wave-broadcast; W reads are coalesced float4.
// ---------------------------------------------------------------------------
__device__ __forceinline__ void gemm_regs(const float* __restrict__ W,
                                          const float* in_lds,
                                          float4* r, bool do_tanh)
{
    const float4* W4 = (const float4*)W;
#pragma unroll
    for (int g = 0; g < 2; ++g) {
        int gi = threadIdx.x + g * BS;
        int n = gi >> 5, d4 = gi & 31;
        const float* row = in_lds + n * 128;
        float4 acc = make_float4(0.f, 0.f, 0.f, 0.f);
#pragma unroll 8
        for (int i = 0; i < 128; ++i) {
            float a = row[i];
            float4 w = W4[i * 32 + d4];
            acc.x = fmaf(a, w.x, acc.x);
            acc.y = fmaf(a, w.y, acc.y);
            acc.z = fmaf(a, w.z, acc.z);
            acc.w = fmaf(a, w.w, acc.w);
        }
        if (do_tanh) {
            acc.x = tanhf(acc.x); acc.y = tanhf(acc.y);
            acc.z = tanhf(acc.z); acc.w = tanhf(acc.w);
        }
        r[g] = acc;
    }
}

__device__ __forceinline__ void gemm_store(const float* __restrict__ W,
                                           const float* in_lds, float* out_lds,
                                           bool do_tanh)
{
    float4 r[2];
    gemm_regs(W, in_lds, r, do_tanh);
    ((float4*)out_lds)[threadIdx.x] = r[0];
    ((float4*)out_lds)[threadIdx.x + BS] = r[1];
}

// transposed store: out_T[d][n] = res[n][d]   (for conflict-free score dots)
__device__ __forceinline__ void gemm_store_T(const float* __restrict__ W,
                                             const float* in_lds, float* out_lds)
{
    float4 r[2];
    gemm_regs(W, in_lds, r, false);
#pragma unroll
    for (int g = 0; g < 2; ++g) {
        int gi = threadIdx.x + g * BS;
        int n = gi >> 5, d4 = gi & 31;
        out_lds[(d4 * 4 + 0) * 32 + n] = r[g].x;
        out_lds[(d4 * 4 + 1) * 32 + n] = r[g].y;
        out_lds[(d4 * 4 + 2) * 32 + n] = r[g].z;
        out_lds[(d4 * 4 + 3) * 32 + n] = r[g].w;
    }
}

// ---------------------------------------------------------------------------
// Kernel 1: fully fused per-batch critic forward. grid = 256 (one block/CU).
// LDS slots (4 x 4096 floats = 64 KB), aliased over time:
//  S0: oa -> oa_p -> wavp
//  S1: op -> vp -> [0:2048]=G_T[h][i], [2048:3072]=scoresT_T/weight_T[j][a],
//                  [3072:4096]=scores_p/wp[n][p]
//  S2: va -> S_acc
//  S3: t_T -> tp_T -> avp -> [0:2048]=F[a][h]
// ---------------------------------------------------------------------------
__global__ __launch_bounds__(BS) void critic_fused(
    const float* __restrict__ states, const float* __restrict__ policies,
    const float* __restrict__ actions, const float* __restrict__ states_p,
    const float* __restrict__ actions_p,
    const float* __restrict__ Wv, const float* __restrict__ Wvp,
    const float* __restrict__ Wf1, const float* __restrict__ Wf2,
    const float* __restrict__ M, float* __restrict__ out)
{
    __shared__ float S0[4096], S1[4096], S2[4096], S3[4096];
    const int tid = threadIdx.x;
    const int b = blockIdx.x;
    const float scale = 0.08838834764831845f;  // 1/sqrt(128)
    const float invN = 1.0f / 32.0f;

    // ---- phase 0: load oa = [states|actions], op = [states|policies] ----
    {
        const float* st = states + (size_t)b * (32 * 96);
        const float* ac = actions + (size_t)b * (32 * 32);
        const float* po = policies + (size_t)b * (32 * 32);
#pragma unroll
        for (int k = 0; k < 8; ++k) {
            int idx = tid + k * BS;
            int n = idx >> 7, d = idx & 127;
            float sv, pv;
            if (d < 96) { sv = st[n * 96 + d]; pv = sv; }
            else        { sv = ac[n * 32 + d - 96]; pv = po[n * 32 + d - 96]; }
            S0[idx] = sv;
            S1[idx] = pv;
        }
    }
    __syncthreads();

    // ---- phase 1: va = tanh(oa@Wv) -> S2 ; vp = tanh(op@Wv) (regs) ----
    gemm_store(Wv, S0, S2, true);
    float4 vpr[2];
    gemm_regs(Wv, S1, vpr, true);
    __syncthreads();
    ((float4*)S1)[tid] = vpr[0];
    ((float4*)S1)[tid + BS] = vpr[1];
    __syncthreads();

    // ---- phase 2: G_T[h][i] = sum_d (vp[i,d]-va[i,d]) * Wf1[d,h] ----
    {
        float gr[4];
#pragma unroll
        for (int k = 0; k < 4; ++k) {
            int oidx = tid + k * BS;        // 0..2047
            int i = oidx >> 6, hh = oidx & 63;
            float acc = 0.f;
#pragma unroll 4
            for (int d = 0; d < 128; ++d)
                acc = fmaf(S1[i * 128 + d] - S2[i * 128 + d], Wf1[d * 64 + hh], acc);
            gr[k] = acc;
        }
        __syncthreads();
#pragma unroll
        for (int k = 0; k < 4; ++k) {
            int oidx = tid + k * BS;
            int i = oidx >> 6, hh = oidx & 63;
            S1[hh * 32 + i] = gr[k];
        }
        __syncthreads();
    }

    // ---- phase 3: t = oa @ Mq (stored transposed t_T[c][j]) ----
    gemm_store_T(M, S0, S3);
    __syncthreads();

    // ---- phase 4: scoresT_T[j][a] = scale * t[j]·oa[a] ----
    {
        float sc[2];
#pragma unroll
        for (int k = 0; k < 2; ++k) {
            int sidx = tid + k * BS;        // 0..1023
            int a = sidx >> 5, j = sidx & 31;
            float acc = 0.f;
#pragma unroll 4
            for (int c = 0; c < 128; ++c)
                acc = fmaf(S3[c * 32 + j], S0[a * 128 + c], acc);
            sc[k] = acc * scale;
        }
#pragma unroll
        for (int k = 0; k < 2; ++k) {
            int sidx = tid + k * BS;
            int a = sidx >> 5, j = sidx & 31;
            S1[2048 + j * 32 + a] = sc[k];
        }
        __syncthreads();
    }

    // ---- phase 5: softmax over j per row a (weight_T[j][a]) ----
    if (tid < 32) {
        int a = tid;
        float m = -1e30f;
        for (int j = 0; j < 32; ++j) m = fmaxf(m, S1[2048 + j * 32 + a]);
        float s = 0.f;
        for (int j = 0; j < 32; ++j) {
            float e = __expf(S1[2048 + j * 32 + a] - m);
            S1[2048 + j * 32 + a] = e;
            s += e;
        }
        float r = 1.0f / s;
        for (int j = 0; j < 32; ++j) S1[2048 + j * 32 + a] *= r;
    }
    __syncthreads();

    // ---- phase 6: write weight out; S_acc = weight @ va (regs) ----
    {
#pragma unroll
        for (int k = 0; k < 2; ++k) {
            int idx = tid + k * BS;
            if (idx < 1024) {
                int a = idx >> 5, j = idx & 31;
                out[W_OFF + (size_t)b * 1024 + idx] = S1[2048 + j * 32 + a];
            }
        }
        float4 sa[2];
        const float4* va4 = (const float4*)S2;
#pragma unroll
        for (int g = 0; g < 2; ++g) {
            int gi = tid + g * BS;
            int a = gi >> 5, d4 = gi & 31;
            float4 acc = make_float4(0.f, 0.f, 0.f, 0.f);
#pragma unroll 4
            for (int j = 0; j < 32; ++j) {
                float w = S1[2048 + j * 32 + a];
                float4 v = va4[j * 32 + d4];
                acc.x = fmaf(w, v.x, acc.x);
                acc.y = fmaf(w, v.y, acc.y);
                acc.z = fmaf(w, v.z, acc.z);
                acc.w = fmaf(w, v.w, acc.w);
            }
            sa[g] = acc;
        }
        __syncthreads();
        ((float4*)S2)[tid] = sa[0];
        ((float4*)S2)[tid + BS] = sa[1];
        __syncthreads();
    }

    // ---- phase 7: tp = oa @ Mp (transposed), then load oa_p over S0 ----
    gemm_store_T(M + 16384, S0, S3);
    __syncthreads();
    {
        const float* st = states_p + (size_t)b * (32 * 96);
        const float* ac = actions_p + (size_t)b * (32 * 32);
#pragma unroll
        for (int k = 0; k < 8; ++k) {
            int idx = tid + k * BS;
            int n = idx >> 7, d = idx & 127;
            S0[idx] = (d < 96) ? st[n * 96 + d] : ac[n * 32 + d - 96];
        }
    }
    __syncthreads();

    // ---- phase 8: scores_p[n][p] = scale * tp[n]·oap[p] ----
    {
        float sc[2];
#pragma unroll
        for (int k = 0; k < 2; ++k) {
            int sidx = tid + k * BS;        // 0..1023
            int p = sidx >> 5, n = sidx & 31;
            float acc = 0.f;
#pragma unroll 4
            for (int c = 0; c < 128; ++c)
                acc = fmaf(S3[c * 32 + n], S0[p * 128 + c], acc);
            sc[k] = acc * scale;
        }
#pragma unroll
        for (int k = 0; k < 2; ++k) {
            int sidx = tid + k * BS;
            int p = sidx >> 5, n = sidx & 31;
            S1[3072 + n * 32 + p] = sc[k];
        }
        __syncthreads();
    }

    // ---- phase 9: softmax over n per column p (axis=-2) ----
    if (tid < 32) {
        int p = tid;
        float m = -1e30f;
        for (int n = 0; n < 32; ++n) m = fmaxf(m, S1[3072 + n * 32 + p]);
        float s = 0.f;
        for (int n = 0; n < 32; ++n) {
            float e = __expf(S1[3072 + n * 32 + p] - m);
            S1[3072 + n * 32 + p] = e;
            s += e;
        }
        float r = 1.0f / s;
        for (int n = 0; n < 32; ++n) S1[3072 + n * 32 + p] *= r;
    }
    __syncthreads();

    // ---- phase 10: write wp out; avp = tanh(oap@Wvp) -> S3 ----
#pragma unroll
    for (int k = 0; k < 2; ++k) {
        int idx = tid + k * BS;
        if (idx < 1024)
            out[WP_OFF + (size_t)b * 1024 + idx] = S1[3072 + idx];
    }
    gemm_store(Wvp, S0, S3, true);
    __syncthreads();

    // ---- phase 11: wavp[n] = (1/P) * sum_p wp[n,p] * avp[p] -> S0 ----
    {
        const float4* avp4 = (const float4*)S3;
#pragma unroll
        for (int g = 0; g < 2; ++g) {
            int gi = tid + g * BS;
            int n = gi >> 5, d4 = gi & 31;
            float4 acc = make_float4(0.f, 0.f, 0.f, 0.f);
#pragma unroll 4
            for (int p = 0; p < 32; ++p) {
                float w = S1[3072 + n * 32 + p];
                float4 v = avp4[p * 32 + d4];
                acc.x = fmaf(w, v.x, acc.x);
                acc.y = fmaf(w, v.y, acc.y);
                acc.z = fmaf(w, v.z, acc.z);
                acc.w = fmaf(w, v.w, acc.w);
            }
            acc.x *= invN; acc.y *= invN; acc.z *= invN; acc.w *= invN;
            // store into S0 only after all reads of oap are done: need sync
            // (avp gemm above read S0; barrier was after phase 10)
            ((float4*)S0)[gi] = acc;   // safe: phase-10 barrier ordered this
        }
        __syncthreads();
    }

    // ---- phase 12: F[a][h] = (S_acc[a]/N)@Wf1_top + wavp[a]@Wf1_bot -> S3[0:2048]
    {
        const float4* Wf1_4 = (const float4*)Wf1;
        int gi = tid;                      // 512 float4 groups
        int a = gi >> 4, h4 = gi & 15;
        float4 accS = make_float4(0.f, 0.f, 0.f, 0.f);
        float4 accW = make_float4(0.f, 0.f, 0.f, 0.f);
#pragma unroll 4
        for (int d = 0; d < 128; ++d) {
            float s = S2[a * 128 + d];
            float w = S0[a * 128 + d];
            float4 w1 = Wf1_4[d * 16 + h4];
            float4 w2 = Wf1_4[(128 + d) * 16 + h4];
            accS.x = fmaf(s, w1.x, accS.x); accS.y = fmaf(s, w1.y, accS.y);
            accS.z = fmaf(s, w1.z, accS.z); accS.w = fmaf(s, w1.w, accS.w);
            accW.x = fmaf(w, w2.x, accW.x); accW.y = fmaf(w, w2.y, accW.y);
            accW.z = fmaf(w, w2.z, accW.z); accW.w = fmaf(w, w2.w, accW.w);
        }
        float4 F4;
        F4.x = fmaf(accS.x, invN, accW.x);
        F4.y = fmaf(accS.y, invN, accW.y);
        F4.z = fmaf(accS.z, invN, accW.z);
        F4.w = fmaf(accS.w, invN, accW.w);
        ((float4*)S3)[gi] = F4;
        __syncthreads();
    }

    // ---- phase 13: stage 2 — value[b,a,i,:] = lrelu(F[a]+w*G[i]) @ Wf2 ----
    {
        const float4* Wf2_4 = (const float4*)Wf2;   // uniform -> s_load
#pragma unroll
        for (int k = 0; k < 2; ++k) {
            int pair = tid + k * BS;       // 0..1023
            int a = pair >> 5, i = pair & 31;
            float w = S1[2048 + i * 32 + a] * invN;   // weight_T[i][a] = weight[a,i]
            float4 acc[8];
#pragma unroll
            for (int o = 0; o < 8; ++o) acc[o] = make_float4(0.f, 0.f, 0.f, 0.f);
            const float* Fa = S3 + a * 64;
            for (int d = 0; d < 64; ++d) {
                float z = fmaf(w, S1[d * 32 + i], Fa[d]);   // F + w*G
                float h = fmaxf(z, 0.01f * z);              // leaky_relu(0.01)
#pragma unroll
                for (int o = 0; o < 8; ++o) {
                    float4 ww = Wf2_4[d * 8 + o];
                    acc[o].x = fmaf(h, ww.x, acc[o].x);
                    acc[o].y = fmaf(h, ww.y, acc[o].y);
                    acc[o].z = fmaf(h, ww.z, acc[o].z);
                    acc[o].w = fmaf(h, ww.w, acc[o].w);
                }
            }
            float4* op4 = (float4*)(out + (size_t)b * 32768 + (size_t)pair * 32);
#pragma unroll
            for (int o = 0; o < 8; ++o) op4[o] = acc[o];
        }
    }
}

// ---------------------------------------------------------------------------
extern "C" void kernel_launch(void* const* d_in, const int* in_sizes, int n_in,
                              void* d_out, int out_size, void* d_ws, size_t ws_size,
                              hipStream_t stream)
{
    const float* states    = (const float*)d_in[0];
    const float* policies  = (const float*)d_in[1];
    const float* actions   = (const float*)d_in[2];
    const float* states_p  = (const float*)d_in[3];
    const float* actions_p = (const float*)d_in[4];
    const float* Wk        = (const float*)d_in[5];
    const float* Wq        = (const float*)d_in[6];
    const float* Wv        = (const float*)d_in[7];
    const float* Wkp       = (const float*)d_in[8];
    const float* Wqp       = (const float*)d_in[9];
    const float* Wvp       = (const float*)d_in[10];
    const float* Wf1       = (const float*)d_in[11];
    const float* Wf2       = (const float*)d_in[12];
    float* out = (float*)d_out;
    float* M   = (float*)d_ws;   // 32768 floats: Mq | Mp

    mm_precompute<<<128, 256, 0, stream>>>(Wq, Wk, Wqp, Wkp, M);
    critic_fused<<<256, BS, 0, stream>>>(states, policies, actions,
                                         states_p, actions_p,
                                         Wv, Wvp, Wf1, Wf2, M, out);
}

// Round 2
// 229.945 us; speedup vs baseline: 1.0664x; 1.0664x over previous
//
#include <hip/hip_runtime.h>
#include <math.h>

// Shapes: B=256, N=P=32, OBS=96, ACT=32, DIN=DOUT=128, DF1=64, DF2=32
#define BS 512
#define VAL_SZ  (256*32*32*32)         // 8388608
#define W_OFF   VAL_SZ
#define WP_OFF  (VAL_SZ + 256*32*32)

// ws layout in floats
#define WS_M 0                          // 2*16384 (Mq|Mp, pre-scaled by 1/sqrt(128))
#define WS_F 32768                      // 256*2048  F[b][a][64]
#define WS_G (32768 + 256*2048)         // 256*2048  G[b][i][64]

// ---------------------------------------------------------------------------
// Kernel 0: M = (Wq @ Wk^T) * scale  and  (Wqp @ Wkp^T) * scale
// ---------------------------------------------------------------------------
__global__ __launch_bounds__(256) void mm_precompute(
    const float* __restrict__ Wq, const float* __restrict__ Wk,
    const float* __restrict__ Wqp, const float* __restrict__ Wkp,
    float* __restrict__ M)
{
    int gid = blockIdx.x * 256 + threadIdx.x;   // 0..32767
    int mat = gid >> 14;
    int idx = gid & 16383;
    int r = idx >> 7, c = idx & 127;
    const float* A  = (mat == 0) ? Wq : Wqp;
    const float* Bm = (mat == 0) ? Wk : Wkp;
    const float4* a4 = (const float4*)(A + r * 128);
    const float4* b4 = (const float4*)(Bm + c * 128);
    float acc = 0.f;
#pragma unroll
    for (int t = 0; t < 32; ++t) {
        float4 x = a4[t], y = b4[t];
        acc = fmaf(x.x, y.x, acc);
        acc = fmaf(x.y, y.y, acc);
        acc = fmaf(x.z, y.z, acc);
        acc = fmaf(x.w, y.w, acc);
    }
    M[gid] = acc * 0.08838834764831845f;        // fold 1/sqrt(128)
}

__device__ __forceinline__ float4 tanh4(float4 v) {
    v.x = tanhf(v.x); v.y = tanhf(v.y); v.z = tanhf(v.z); v.w = tanhf(v.w);
    return v;
}

// ---------------------------------------------------------------------------
// 32x128 @ 128x128 GEMM, 4 rows/thread, K split in halves across lane bit 5,
// reduced with shfl_xor(32).  W traffic per block: 512KB (vs 2MB naive).
// Thread map: d4 = t&31 (out col group), kh = (t>>5)&1 (K half), ng = t>>6.
// Rows handled: ng, ng+8, ng+16, ng+24.  kh0 writes rows {ng,ng+8},
// kh1 writes rows {ng+16,ng+24}.
// sub_lds != nullptr: out = tanh(acc) - sub   (used to emit delta = vp - va)
// ---------------------------------------------------------------------------
__device__ __forceinline__ void gemm4(const float* __restrict__ W,
                                      const float* in_lds, float* out_lds,
                                      bool do_tanh, bool pre_barrier,
                                      const float* sub_lds)
{
    const int t  = threadIdx.x;
    const int d4 = t & 31;
    const int kh = (t >> 5) & 1;
    const int ng = t >> 6;
    const float4* W4 = (const float4*)W;
    float4 a0 = make_float4(0,0,0,0), a1 = a0, a2 = a0, a3 = a0;
    const float* r0 = in_lds + (ng +  0) * 128;
    const float* r1 = in_lds + (ng +  8) * 128;
    const float* r2 = in_lds + (ng + 16) * 128;
    const float* r3 = in_lds + (ng + 24) * 128;
    const int ib = kh * 64;
#pragma unroll 8
    for (int ii = 0; ii < 64; ++ii) {
        int i = ib + ii;
        float4 w = W4[i * 32 + d4];
        float x0 = r0[i], x1 = r1[i], x2 = r2[i], x3 = r3[i];
        a0.x = fmaf(x0,w.x,a0.x); a0.y = fmaf(x0,w.y,a0.y); a0.z = fmaf(x0,w.z,a0.z); a0.w = fmaf(x0,w.w,a0.w);
        a1.x = fmaf(x1,w.x,a1.x); a1.y = fmaf(x1,w.y,a1.y); a1.z = fmaf(x1,w.z,a1.z); a1.w = fmaf(x1,w.w,a1.w);
        a2.x = fmaf(x2,w.x,a2.x); a2.y = fmaf(x2,w.y,a2.y); a2.z = fmaf(x2,w.z,a2.z); a2.w = fmaf(x2,w.w,a2.w);
        a3.x = fmaf(x3,w.x,a3.x); a3.y = fmaf(x3,w.y,a3.y); a3.z = fmaf(x3,w.z,a3.z); a3.w = fmaf(x3,w.w,a3.w);
    }
    // cross-K-half reduction (lanes l <-> l+32 share d4/ng)
    a0.x += __shfl_xor(a0.x, 32); a0.y += __shfl_xor(a0.y, 32); a0.z += __shfl_xor(a0.z, 32); a0.w += __shfl_xor(a0.w, 32);
    a1.x += __shfl_xor(a1.x, 32); a1.y += __shfl_xor(a1.y, 32); a1.z += __shfl_xor(a1.z, 32); a1.w += __shfl_xor(a1.w, 32);
    a2.x += __shfl_xor(a2.x, 32); a2.y += __shfl_xor(a2.y, 32); a2.z += __shfl_xor(a2.z, 32); a2.w += __shfl_xor(a2.w, 32);
    a3.x += __shfl_xor(a3.x, 32); a3.y += __shfl_xor(a3.y, 32); a3.z += __shfl_xor(a3.z, 32); a3.w += __shfl_xor(a3.w, 32);

    if (pre_barrier) __syncthreads();

    int ra = ng + kh * 16;          // kh0: ng ; kh1: ng+16
    int rb = ra + 8;
    float4 va = kh ? a2 : a0;
    float4 vb = kh ? a3 : a1;
    if (do_tanh) { va = tanh4(va); vb = tanh4(vb); }
    if (sub_lds) {
        const float4* s4 = (const float4*)sub_lds;
        float4 sa = s4[ra * 32 + d4], sb = s4[rb * 32 + d4];
        va.x -= sa.x; va.y -= sa.y; va.z -= sa.z; va.w -= sa.w;
        vb.x -= sb.x; vb.y -= sb.y; vb.z -= sb.z; vb.w -= sb.w;
    }
    ((float4*)out_lds)[ra * 32 + d4] = va;
    ((float4*)out_lds)[rb * 32 + d4] = vb;
}

// ---------------------------------------------------------------------------
// Kernel A: per-batch phases 0-12. grid 256, 512 threads, 64KB LDS exactly.
// Slots: SA: oa -> [0:1056]=scores_p/wp (pad 33)
//        SB: op -> delta(vp-va) -> [0:1056]=scores/weight_T (pad 33) -> oap -> wavp
//        SC: va -> S_acc
//        SD: t -> tp -> avp
// ---------------------------------------------------------------------------
__global__ __launch_bounds__(BS) void critic_A(
    const float* __restrict__ states, const float* __restrict__ policies,
    const float* __restrict__ actions, const float* __restrict__ states_p,
    const float* __restrict__ actions_p,
    const float* __restrict__ Wv, const float* __restrict__ Wvp,
    const float* __restrict__ Wf1, float* __restrict__ ws,
    float* __restrict__ out)
{
    __shared__ float SA[4096], SB[4096], SC[4096], SD[4096];
    const int tid = threadIdx.x;
    const int b = blockIdx.x;
    const float invN = 1.0f / 32.0f;
    const float* M = ws + WS_M;

    // ---- P0: oa -> SA, op -> SB (plain row-major, coalesced) ----
    {
        const float* st = states   + (size_t)b * (32 * 96);
        const float* ac = actions  + (size_t)b * (32 * 32);
        const float* po = policies + (size_t)b * (32 * 32);
#pragma unroll
        for (int k = 0; k < 8; ++k) {
            int idx = tid + k * BS;
            int n = idx >> 7, d = idx & 127;
            float sv, pv;
            if (d < 96) { sv = st[n * 96 + d]; pv = sv; }
            else        { sv = ac[n * 32 + d - 96]; pv = po[n * 32 + d - 96]; }
            SA[idx] = sv;
            SB[idx] = pv;
        }
    }
    __syncthreads();

    // ---- P1: va = tanh(oa@Wv) -> SC ; delta = tanh(op@Wv) - va -> SB ----
    gemm4(Wv, SA, SC, true, false, nullptr);
    gemm4(Wv, SB, SB, true, true, SC);   // pre-barrier: op reads before overwrite
    __syncthreads();

    // ---- P2: G[i][h] = sum_d delta[i,d]*Wf1[d,h] -> ws (coalesced) ----
    {
        int hh = tid & 63, i0 = tid >> 6;     // i0 uniform per wave
        float acc[4] = {0.f, 0.f, 0.f, 0.f};
#pragma unroll 4
        for (int d = 0; d < 128; ++d) {
            float w = Wf1[d * 64 + hh];
            acc[0] = fmaf(SB[(i0 +  0) * 128 + d], w, acc[0]);
            acc[1] = fmaf(SB[(i0 +  8) * 128 + d], w, acc[1]);
            acc[2] = fmaf(SB[(i0 + 16) * 128 + d], w, acc[2]);
            acc[3] = fmaf(SB[(i0 + 24) * 128 + d], w, acc[3]);
        }
        float* g = ws + WS_G + (size_t)b * 2048;
        g[(i0 +  0) * 64 + hh] = acc[0];
        g[(i0 +  8) * 64 + hh] = acc[1];
        g[(i0 + 16) * 64 + hh] = acc[2];
        g[(i0 + 24) * 64 + hh] = acc[3];
    }

    // ---- P3: t = oa @ Mq(scaled) -> SD ----
    gemm4(M, SA, SD, false, false, nullptr);
    __syncthreads();

    // ---- P4: scores[j,a] = t[j]·oa[a] -> SB1[j*33+a] (rotated-start dot) ----
    {
        float sc[2];
#pragma unroll
        for (int k = 0; k < 2; ++k) {
            int sidx = tid + k * BS;
            int j = sidx >> 5, a = sidx & 31;
            const float* tj = SD + j * 128;
            const float* oa = SA + a * 128;
            int c = (5 * a) & 127;
            float acc = 0.f;
#pragma unroll 8
            for (int s = 0; s < 128; ++s) {
                acc = fmaf(tj[c], oa[c], acc);
                c = (c + 1) & 127;
            }
            sc[k] = acc;
        }
#pragma unroll
        for (int k = 0; k < 2; ++k) {
            int sidx = tid + k * BS;
            int j = sidx >> 5, a = sidx & 31;
            SB[j * 33 + a] = sc[k];
        }
        __syncthreads();
    }

    // ---- P5: softmax over j per a (shuffle, 32 lanes per column) ----
    {
        int j = tid & 31, ab = tid >> 5;      // ab: 0..15
#pragma unroll
        for (int rep = 0; rep < 2; ++rep) {
            int a = ab + rep * 16;
            float x = SB[j * 33 + a];
            float m = x;
#pragma unroll
            for (int msk = 16; msk >= 1; msk >>= 1) m = fmaxf(m, __shfl_xor(m, msk));
            float e = __expf(x - m);
            float s = e;
#pragma unroll
            for (int msk = 16; msk >= 1; msk >>= 1) s += __shfl_xor(s, msk);
            SB[j * 33 + a] = e / s;
        }
    }
    __syncthreads();

    // ---- P6: export weight; S_acc = weight @ va -> SC ----
    {
#pragma unroll
        for (int k = 0; k < 2; ++k) {
            int idx = tid + k * BS;
            int a = idx >> 5, j = idx & 31;
            out[W_OFF + (size_t)b * 1024 + idx] = SB[j * 33 + a];
        }
        float4 sa[2];
        const float4* va4 = (const float4*)SC;
#pragma unroll
        for (int g = 0; g < 2; ++g) {
            int gi = tid + g * BS;
            int a = gi >> 5, d4 = gi & 31;
            float4 acc = make_float4(0.f, 0.f, 0.f, 0.f);
#pragma unroll 4
            for (int j = 0; j < 32; ++j) {
                float w = SB[j * 33 + a];
                float4 v = va4[j * 32 + d4];
                acc.x = fmaf(w, v.x, acc.x);
                acc.y = fmaf(w, v.y, acc.y);
                acc.z = fmaf(w, v.z, acc.z);
                acc.w = fmaf(w, v.w, acc.w);
            }
            sa[g] = acc;
        }
        __syncthreads();
        ((float4*)SC)[tid] = sa[0];
        ((float4*)SC)[tid + BS] = sa[1];
    }

    // ---- P7: tp = oa @ Mp(scaled) -> SD ; load oap -> SB ----
    gemm4(M + 16384, SA, SD, false, false, nullptr);
    {
        const float* st = states_p  + (size_t)b * (32 * 96);
        const float* ac = actions_p + (size_t)b * (32 * 32);
#pragma unroll
        for (int k = 0; k < 8; ++k) {
            int idx = tid + k * BS;
            int n = idx >> 7, d = idx & 127;
            SB[idx] = (d < 96) ? st[n * 96 + d] : ac[n * 32 + d - 96];
        }
    }
    __syncthreads();

    // ---- P8: scores_p[n,p] = tp[n]·oap[p] -> SA1[n*33+p] ----
    {
        float sc[2];
#pragma unroll
        for (int k = 0; k < 2; ++k) {
            int sidx = tid + k * BS;
            int n = sidx >> 5, p = sidx & 31;
            const float* tn = SD + n * 128;
            const float* op = SB + p * 128;
            int c = (5 * p) & 127;
            float acc = 0.f;
#pragma unroll 8
            for (int s = 0; s < 128; ++s) {
                acc = fmaf(tn[c], op[c], acc);
                c = (c + 1) & 127;
            }
            sc[k] = acc;
        }
#pragma unroll
        for (int k = 0; k < 2; ++k) {
            int sidx = tid + k * BS;
            int n = sidx >> 5, p = sidx & 31;
            SA[n * 33 + p] = sc[k];
        }
        __syncthreads();
    }

    // ---- P9: softmax over n per p (axis=-2) ----
    {
        int n = tid & 31, pb = tid >> 5;
#pragma unroll
        for (int rep = 0; rep < 2; ++rep) {
            int p = pb + rep * 16;
            float x = SA[n * 33 + p];
            float m = x;
#pragma unroll
            for (int msk = 16; msk >= 1; msk >>= 1) m = fmaxf(m, __shfl_xor(m, msk));
            float e = __expf(x - m);
            float s = e;
#pragma unroll
            for (int msk = 16; msk >= 1; msk >>= 1) s += __shfl_xor(s, msk);
            SA[n * 33 + p] = e / s;
        }
    }
    __syncthreads();

    // ---- P10: export wp; avp = tanh(oap @ Wvp) -> SD ----
#pragma unroll
    for (int k = 0; k < 2; ++k) {
        int idx = tid + k * BS;
        int n = idx >> 5, p = idx & 31;
        out[WP_OFF + (size_t)b * 1024 + idx] = SA[n * 33 + p];
    }
    gemm4(Wvp, SB, SD, true, false, nullptr);
    __syncthreads();

    // ---- P11: wavp[n] = (1/P) * sum_p wp[n,p]*avp[p] -> SB ----
    {
        float4 wv[2];
        const float4* avp4 = (const float4*)SD;
#pragma unroll
        for (int g = 0; g < 2; ++g) {
            int gi = tid + g * BS;
            int n = gi >> 5, d4 = gi & 31;
            float4 acc = make_float4(0.f, 0.f, 0.f, 0.f);
#pragma unroll 4
            for (int p = 0; p < 32; ++p) {
                float w = SA[n * 33 + p];
                float4 v = avp4[p * 32 + d4];
                acc.x = fmaf(w, v.x, acc.x);
                acc.y = fmaf(w, v.y, acc.y);
                acc.z = fmaf(w, v.z, acc.z);
                acc.w = fmaf(w, v.w, acc.w);
            }
            acc.x *= invN; acc.y *= invN; acc.z *= invN; acc.w *= invN;
            wv[g] = acc;
        }
        __syncthreads();
        ((float4*)SB)[tid] = wv[0];
        ((float4*)SB)[tid + BS] = wv[1];
    }
    __syncthreads();

    // ---- P12: F[a][h] = (S_acc[a]/N)@Wf1_top + wavp[a]@Wf1_bot -> ws ----
    {
        int h4 = tid & 15;
        int kh = (tid >> 5) & 1;
        int ap = ((tid >> 6) << 1) | ((tid >> 4) & 1);   // 0..15
        int a0 = ap, a1 = ap + 16;
        const float4* W14 = (const float4*)Wf1;
        float4 s0 = make_float4(0,0,0,0), w0 = s0, s1 = s0, w1acc = s0;
        const int db = kh * 64;
#pragma unroll 4
        for (int dd = 0; dd < 64; ++dd) {
            int d = db + dd;
            float4 w1 = W14[d * 16 + h4];
            float4 w2 = W14[(128 + d) * 16 + h4];
            float xa = SC[a0 * 128 + d], xb = SC[a1 * 128 + d];
            float ya = SB[a0 * 128 + d], yb = SB[a1 * 128 + d];
            s0.x = fmaf(xa,w1.x,s0.x); s0.y = fmaf(xa,w1.y,s0.y); s0.z = fmaf(xa,w1.z,s0.z); s0.w = fmaf(xa,w1.w,s0.w);
            s1.x = fmaf(xb,w1.x,s1.x); s1.y = fmaf(xb,w1.y,s1.y); s1.z = fmaf(xb,w1.z,s1.z); s1.w = fmaf(xb,w1.w,s1.w);
            w0.x = fmaf(ya,w2.x,w0.x); w0.y = fmaf(ya,w2.y,w0.y); w0.z = fmaf(ya,w2.z,w0.z); w0.w = fmaf(ya,w2.w,w0.w);
            w1acc.x = fmaf(yb,w2.x,w1acc.x); w1acc.y = fmaf(yb,w2.y,w1acc.y);
            w1acc.z = fmaf(yb,w2.z,w1acc.z); w1acc.w = fmaf(yb,w2.w,w1acc.w);
        }
        float4 F0, F1;
        F0.x = fmaf(s0.x, invN, w0.x); F0.y = fmaf(s0.y, invN, w0.y);
        F0.z = fmaf(s0.z, invN, w0.z); F0.w = fmaf(s0.w, invN, w0.w);
        F1.x = fmaf(s1.x, invN, w1acc.x); F1.y = fmaf(s1.y, invN, w1acc.y);
        F1.z = fmaf(s1.z, invN, w1acc.z); F1.w = fmaf(s1.w, invN, w1acc.w);
        F0.x += __shfl_xor(F0.x, 32); F0.y += __shfl_xor(F0.y, 32);
        F0.z += __shfl_xor(F0.z, 32); F0.w += __shfl_xor(F0.w, 32);
        F1.x += __shfl_xor(F1.x, 32); F1.y += __shfl_xor(F1.y, 32);
        F1.z += __shfl_xor(F1.z, 32); F1.w += __shfl_xor(F1.w, 32);
        float4* f4 = (float4*)(ws + WS_F + (size_t)b * 2048);
        int aw = kh ? a1 : a0;
        f4[aw * 16 + h4] = kh ? F1 : F0;
    }
}

// ---------------------------------------------------------------------------
// Kernel B: value[b,a,i,:] = lrelu(F[a] + (weight[a,i]/N)*G[i]) @ Wf2
// grid 1024 (b x 4 a-chunks), 256 threads, no LDS -> high occupancy.
// ---------------------------------------------------------------------------
__global__ __launch_bounds__(256) void critic_B(
    const float* __restrict__ ws, const float* __restrict__ Wf2,
    float* __restrict__ out)
{
    int blk = blockIdx.x;
    int b = blk >> 2, ch = blk & 3;
    int i = threadIdx.x & 31;
    int a = ch * 8 + (threadIdx.x >> 5);
    float w = out[W_OFF + (size_t)b * 1024 + a * 32 + i] * (1.0f / 32.0f);
    const float* F = ws + WS_F + (size_t)b * 2048 + a * 64;
    const float* G = ws + WS_G + (size_t)b * 2048 + i * 64;
    const float4* W2 = (const float4*)Wf2;     // lane-uniform -> scalar loads
    float4 acc[8];
#pragma unroll
    for (int o = 0; o < 8; ++o) acc[o] = make_float4(0.f, 0.f, 0.f, 0.f);
#pragma unroll 8
    for (int d = 0; d < 64; ++d) {
        float z = fmaf(w, G[d], F[d]);
        float h = fmaxf(z, 0.01f * z);
#pragma unroll
        for (int o = 0; o < 8; ++o) {
            float4 ww = W2[d * 8 + o];
            acc[o].x = fmaf(h, ww.x, acc[o].x);
            acc[o].y = fmaf(h, ww.y, acc[o].y);
            acc[o].z = fmaf(h, ww.z, acc[o].z);
            acc[o].w = fmaf(h, ww.w, acc[o].w);
        }
    }
    float4* op4 = (float4*)(out + (size_t)b * 32768 + a * 1024 + i * 32);
#pragma unroll
    for (int o = 0; o < 8; ++o) op4[o] = acc[o];
}

// ---------------------------------------------------------------------------
extern "C" void kernel_launch(void* const* d_in, const int* in_sizes, int n_in,
                              void* d_out, int out_size, void* d_ws, size_t ws_size,
                              hipStream_t stream)
{
    const float* states    = (const float*)d_in[0];
    const float* policies  = (const float*)d_in[1];
    const float* actions   = (const float*)d_in[2];
    const float* states_p  = (const float*)d_in[3];
    const float* actions_p = (const float*)d_in[4];
    const float* Wk        = (const float*)d_in[5];
    const float* Wq        = (const float*)d_in[6];
    const float* Wv        = (const float*)d_in[7];
    const float* Wkp       = (const float*)d_in[8];
    const float* Wqp       = (const float*)d_in[9];
    const float* Wvp       = (const float*)d_in[10];
    const float* Wf1       = (const float*)d_in[11];
    const float* Wf2       = (const float*)d_in[12];
    float* out = (float*)d_out;
    float* ws  = (float*)d_ws;

    mm_precompute<<<128, 256, 0, stream>>>(Wq, Wk, Wqp, Wkp, ws + WS_M);
    critic_A<<<256, BS, 0, stream>>>(states, policies, actions,
                                     states_p, actions_p,
                                     Wv, Wvp, Wf1, ws, out);
    critic_B<<<1024, 256, 0, stream>>>(ws, Wf2, out);
}

// Round 3
// 169.956 us; speedup vs baseline: 1.4428x; 1.3530x over previous
//
#include <hip/hip_runtime.h>
#include <math.h>

// Shapes: B=256, N=P=32, OBS=96, ACT=32, DIN=DOUT=128, DF1=64, DF2=32
#define VAL_SZ  (256*32*32*32)
#define W_OFF   VAL_SZ
#define WP_OFF  (VAL_SZ + 256*32*32)

// ws layout: [packed bf16 weights 163840 B][F f32][G f32]
#define PK_WV   0            // ushort offsets
#define PK_WVP  16384
#define PK_MQ   32768
#define PK_MP   49152
#define PK_WF1  65536        // 256x64 packed (kt 0..7, nt 0..3)
#define WS_F    49152        // float offset
#define WS_G    (49152 + 256*2048)

typedef short  bf16x8 __attribute__((ext_vector_type(8)));
typedef float  f32x4  __attribute__((ext_vector_type(4)));

#define MFMA(a, b, c) __builtin_amdgcn_mfma_f32_16x16x32_bf16(a, b, c, 0, 0, 0)

static __device__ __forceinline__ unsigned short f2bf(float f) {
    union { float f; unsigned u; } v; v.f = f;
    unsigned r = (v.u + 0x7FFF + ((v.u >> 16) & 1)) >> 16;
    return (unsigned short)r;
}

// A-frag / row-read B-frag from row-major bf16 LDS (stride in ushorts, mult of 8)
static __device__ __forceinline__ bf16x8 afrag(const unsigned short* Mb, int stride,
                                               int row0, int kt) {
    int lane = threadIdx.x & 63;
    return *(const bf16x8*)(Mb + (row0 + (lane & 15)) * stride + kt * 32 + (lane >> 4) * 8);
}

// B-frag from packed global weights
static __device__ __forceinline__ bf16x8 bfrag_pk(const unsigned short* base, int NT,
                                                  int kt, int nt) {
    int lane = threadIdx.x & 63;
    return *(const bf16x8*)(base + (((kt * NT + nt) * 64) + lane) * 8);
}

// ---------------------------------------------------------------------------
// Kernel 0: pack Wv, Wvp, Wf1 and computed Mq=(Wq@Wk^T)*s, Mp=(Wqp@Wkp^T)*s
// into bf16 B-fragment order: pk[mat][(kt*NT+nt)*64 + lane] = 8 bf16 (j fast).
// Element: B[kt*32 + (lane>>4)*8 + j][nt*16 + (lane&15)].
// ---------------------------------------------------------------------------
__global__ __launch_bounds__(256) void pack_weights(
    const float* __restrict__ Wq, const float* __restrict__ Wk,
    const float* __restrict__ Wv, const float* __restrict__ Wkp,
    const float* __restrict__ Wqp, const float* __restrict__ Wvp,
    const float* __restrict__ Wf1, unsigned short* __restrict__ pk)
{
    int gid = blockIdx.x * 256 + threadIdx.x;     // 0..10239
    if (gid >= 10240) return;
    int mat = gid >> 11;                          // 0..4
    int r = gid & 2047;
    int lane = r & 63;
    int l16 = lane & 15, quad = lane >> 4;
    const float scale = 0.08838834764831845f;     // 1/sqrt(128)
    union { unsigned short u[8]; bf16x8 v; } out;
    unsigned short* base;
    int ktnt;

    if (mat == 0 || mat == 1) {                   // Wv / Wvp: 128x128, NT=8
        const float* W = (mat == 0) ? Wv : Wvp;
        ktnt = r >> 6;
        int kt = ktnt >> 3, nt = ktnt & 7;
        int n = nt * 16 + l16;
#pragma unroll
        for (int j = 0; j < 8; ++j) {
            int k = kt * 32 + quad * 8 + j;
            out.u[j] = f2bf(W[k * 128 + n]);
        }
        base = pk + ((mat == 0) ? PK_WV : PK_WVP);
    } else if (mat == 4) {                        // Wf1: 256x64, NT=4
        ktnt = r >> 6;
        int kt = ktnt >> 2, nt = ktnt & 3;
        int n = nt * 16 + l16;
#pragma unroll
        for (int j = 0; j < 8; ++j) {
            int k = kt * 32 + quad * 8 + j;
            out.u[j] = f2bf(Wf1[k * 64 + n]);
        }
        base = pk + PK_WF1;
    } else {                                      // Mq (2) / Mp (3): 128x128, NT=8
        const float* A  = (mat == 2) ? Wq : Wqp;
        const float* Bm = (mat == 2) ? Wk : Wkp;
        ktnt = r >> 6;
        int kt = ktnt >> 3, nt = ktnt & 7;
        int n = nt * 16 + l16;
        const float4* b4 = (const float4*)(Bm + n * 128);
#pragma unroll
        for (int j = 0; j < 8; ++j) {
            int k = kt * 32 + quad * 8 + j;
            const float4* a4 = (const float4*)(A + k * 128);
            float acc = 0.f;
#pragma unroll 8
            for (int c = 0; c < 32; ++c) {
                float4 x = a4[c], y = b4[c];
                acc = fmaf(x.x, y.x, acc);
                acc = fmaf(x.y, y.y, acc);
                acc = fmaf(x.z, y.z, acc);
                acc = fmaf(x.w, y.w, acc);
            }
            out.u[j] = f2bf(acc * scale);
        }
        base = pk + ((mat == 2) ? PK_MQ : PK_MP);
    }
    *(bf16x8*)(base + (ktnt * 64 + lane) * 8) = out.v;
}

// ---------------------------------------------------------------------------
// Kernel A: per-batch forward via bf16 MFMA. grid 256 x 512 thr (8 waves).
// LDS (57 KB): OA[32x136]+T[32x136] (aliased by NF[32x264] late), OP/OAP[32x136],
// VT=vaT/avpT[128x40], SC1/SC2 fp32 [32x33], WB1/WB2 bf16 [32x40], TP[32x136].
// ---------------------------------------------------------------------------
__global__ __launch_bounds__(512) void critic_A(
    const float* __restrict__ states, const float* __restrict__ policies,
    const float* __restrict__ actions, const float* __restrict__ states_p,
    const float* __restrict__ actions_p,
    const unsigned short* __restrict__ pk,
    float* __restrict__ ws, float* __restrict__ out)
{
    __shared__ __align__(16) unsigned char SM[58624];
    unsigned short* OA  = (unsigned short*)(SM + 0);       // 32 x 136
    unsigned short* T   = (unsigned short*)(SM + 8704);    // delta -> t
    unsigned short* NF  = (unsigned short*)(SM + 0);       // 32 x 264 (aliases OA+T)
    unsigned short* OP  = (unsigned short*)(SM + 17408);   // op -> oap
    unsigned short* VT  = (unsigned short*)(SM + 26112);   // vaT -> avpT, 128 x 40
    float*          SC1 = (float*)(SM + 36352);            // 32 x 33
    float*          SC2 = (float*)(SM + 40576);
    unsigned short* WB1 = (unsigned short*)(SM + 44800);   // weight bf16 32 x 40
    unsigned short* WB2 = (unsigned short*)(SM + 47360);   // wp bf16
    unsigned short* TP  = (unsigned short*)(SM + 49920);   // tp 32 x 136

    const int tid = threadIdx.x;
    const int b = blockIdx.x;
    const int lane = tid & 63, wv = tid >> 6;
    const int l16 = lane & 15, quad = lane >> 4;
    const float invN = 1.0f / 32.0f;
    const f32x4 Z = {0.f, 0.f, 0.f, 0.f};

    // ---- P0: load oa, op -> bf16 LDS ----
    {
        const float* st = states   + (size_t)b * 3072;
        const float* ac = actions  + (size_t)b * 1024;
        const float* po = policies + (size_t)b * 1024;
#pragma unroll
        for (int k = 0; k < 8; ++k) {
            int idx = tid + k * 512;
            int n = idx >> 7, d = idx & 127;
            float sv, pv;
            if (d < 96) { sv = st[n * 96 + d]; pv = sv; }
            else        { sv = ac[n * 32 + d - 96]; pv = po[n * 32 + d - 96]; }
            OA[n * 136 + d] = f2bf(sv);
            OP[n * 136 + d] = f2bf(pv);
        }
    }
    __syncthreads();

    // ---- P1: va = tanh(oa@Wv) -> vaT; delta = tanh(op@Wv) - va -> T ----
    {
        int mt = wv & 1, ntA = wv >> 1, ntB = ntA + 4;
        f32x4 va0 = Z, va1 = Z, vp0 = Z, vp1 = Z;
#pragma unroll
        for (int kt = 0; kt < 4; ++kt) {
            bf16x8 aA = afrag(OA, 136, mt * 16, kt);
            bf16x8 aP = afrag(OP, 136, mt * 16, kt);
            bf16x8 b0 = bfrag_pk(pk + PK_WV, 8, kt, ntA);
            bf16x8 b1 = bfrag_pk(pk + PK_WV, 8, kt, ntB);
            va0 = MFMA(aA, b0, va0); va1 = MFMA(aA, b1, va1);
            vp0 = MFMA(aP, b0, vp0); vp1 = MFMA(aP, b1, vp1);
        }
#pragma unroll
        for (int r = 0; r < 4; ++r) {
            int row = mt * 16 + quad * 4 + r;
            float tva0 = tanhf(va0[r]), tvp0 = tanhf(vp0[r]);
            float tva1 = tanhf(va1[r]), tvp1 = tanhf(vp1[r]);
            VT[(ntA * 16 + l16) * 40 + row] = f2bf(tva0);
            VT[(ntB * 16 + l16) * 40 + row] = f2bf(tva1);
            T[row * 136 + ntA * 16 + l16] = f2bf(tvp0 - tva0);
            T[row * 136 + ntB * 16 + l16] = f2bf(tvp1 - tva1);
        }
    }
    __syncthreads();

    // ---- P2: G = delta @ Wf1_top -> ws.G ; also load oap -> OP ----
    {
        int mt = wv & 1, nt = wv >> 1;      // 2x4 tiles of 32x64
        f32x4 g = Z;
#pragma unroll
        for (int kt = 0; kt < 4; ++kt)
            g = MFMA(afrag(T, 136, mt * 16, kt), bfrag_pk(pk + PK_WF1, 4, kt, nt), g);
        float* Gp = ws + WS_G + (size_t)b * 2048;
#pragma unroll
        for (int r = 0; r < 4; ++r)
            Gp[(mt * 16 + quad * 4 + r) * 64 + nt * 16 + l16] = g[r];

        const float* st = states_p  + (size_t)b * 3072;
        const float* ac = actions_p + (size_t)b * 1024;
#pragma unroll
        for (int k = 0; k < 8; ++k) {
            int idx = tid + k * 512;
            int n = idx >> 7, d = idx & 127;
            OP[n * 136 + d] = f2bf((d < 96) ? st[n * 96 + d] : ac[n * 32 + d - 96]);
        }
    }
    __syncthreads();

    // ---- P3: t = oa@Mq -> T (waves 0-3); tp = oa@Mp -> TP (waves 4-7) ----
    {
        int half = wv >> 2;
        int w4 = wv & 3;
        int mt = w4 & 1, ntb = w4 >> 1;     // nt in {ntb, ntb+2, ntb+4, ntb+6}
        const unsigned short* pkM = pk + (half ? PK_MP : PK_MQ);
        unsigned short* outT = half ? TP : T;
        bf16x8 afr[4];
#pragma unroll
        for (int kt = 0; kt < 4; ++kt) afr[kt] = afrag(OA, 136, mt * 16, kt);
#pragma unroll
        for (int t4 = 0; t4 < 4; ++t4) {
            int nt = ntb + t4 * 2;
            f32x4 acc = Z;
#pragma unroll
            for (int kt = 0; kt < 4; ++kt)
                acc = MFMA(afr[kt], bfrag_pk(pkM, 8, kt, nt), acc);
#pragma unroll
            for (int r = 0; r < 4; ++r)
                outT[(mt * 16 + quad * 4 + r) * 136 + nt * 16 + l16] = f2bf(acc[r]);
        }
    }
    __syncthreads();

    // ---- P4: scores[j,a] = t@oa^T -> SC1; scores_p[n,p] = tp@oap^T -> SC2 ----
    {
        int half = wv >> 2;
        int w4 = wv & 3;
        int mt = w4 & 1, nt = w4 >> 1;
        const unsigned short* Am = half ? TP : T;
        const unsigned short* Bm = half ? OP : OA;
        float* SC = half ? SC2 : SC1;
        f32x4 acc = Z;
#pragma unroll
        for (int kt = 0; kt < 4; ++kt)
            acc = MFMA(afrag(Am, 136, mt * 16, kt), afrag(Bm, 136, nt * 16, kt), acc);
#pragma unroll
        for (int r = 0; r < 4; ++r)
            SC[(mt * 16 + quad * 4 + r) * 33 + nt * 16 + l16] = acc[r];
    }
    __syncthreads();

    // ---- P5: softmaxes; export weight/wp fp32; stash bf16 copies ----
    {
        int j = tid & 31, ab = tid >> 5;       // weight: softmax over j per a
#pragma unroll
        for (int rep = 0; rep < 2; ++rep) {
            int a = ab + rep * 16;
            float x = SC1[j * 33 + a];
            float m = x;
#pragma unroll
            for (int msk = 16; msk >= 1; msk >>= 1) m = fmaxf(m, __shfl_xor(m, msk));
            float e = __expf(x - m);
            float s = e;
#pragma unroll
            for (int msk = 16; msk >= 1; msk >>= 1) s += __shfl_xor(s, msk);
            float w = e / s;
            out[W_OFF + (size_t)b * 1024 + a * 32 + j] = w;
            WB1[a * 40 + j] = f2bf(w);
        }
        int n = tid & 31, pb = tid >> 5;       // wp: softmax over n per p
#pragma unroll
        for (int rep = 0; rep < 2; ++rep) {
            int p = pb + rep * 16;
            float x = SC2[n * 33 + p];
            float m = x;
#pragma unroll
            for (int msk = 16; msk >= 1; msk >>= 1) m = fmaxf(m, __shfl_xor(m, msk));
            float e = __expf(x - m);
            float s = e;
#pragma unroll
            for (int msk = 16; msk >= 1; msk >>= 1) s += __shfl_xor(s, msk);
            float w = e / s;
            out[WP_OFF + (size_t)b * 1024 + n * 32 + p] = w;
            WB2[n * 40 + p] = f2bf(w);
        }
    }
    __syncthreads();

    // ---- P6a: S_acc = weight@va -> NF[:,0:128]*invN ; avp MFMA into regs ----
    f32x4 av0 = Z, av1 = Z;
    {
        int mt = wv & 1, ntA = wv >> 1, ntB = ntA + 4;
        f32x4 s0 = MFMA(afrag(WB1, 40, mt * 16, 0), afrag(VT, 40, ntA * 16, 0), Z);
        f32x4 s1 = MFMA(afrag(WB1, 40, mt * 16, 0), afrag(VT, 40, ntB * 16, 0), Z);
#pragma unroll
        for (int kt = 0; kt < 4; ++kt) {
            bf16x8 a = afrag(OP, 136, mt * 16, kt);
            av0 = MFMA(a, bfrag_pk(pk + PK_WVP, 8, kt, ntA), av0);
            av1 = MFMA(a, bfrag_pk(pk + PK_WVP, 8, kt, ntB), av1);
        }
#pragma unroll
        for (int r = 0; r < 4; ++r) {
            int row = mt * 16 + quad * 4 + r;
            NF[row * 264 + ntA * 16 + l16] = f2bf(s0[r] * invN);
            NF[row * 264 + ntB * 16 + l16] = f2bf(s1[r] * invN);
        }
    }
    __syncthreads();

    // ---- P6b: avpT -> VT (vaT dead) ----
    {
        int mt = wv & 1, ntA = wv >> 1, ntB = ntA + 4;
#pragma unroll
        for (int r = 0; r < 4; ++r) {
            int row = mt * 16 + quad * 4 + r;        // p index
            VT[(ntA * 16 + l16) * 40 + row] = f2bf(tanhf(av0[r]));
            VT[(ntB * 16 + l16) * 40 + row] = f2bf(tanhf(av1[r]));
        }
    }
    __syncthreads();

    // ---- P6c: wavp = wp@avp -> NF[:,128:256]*invN ----
    {
        int mt = wv & 1, ntA = wv >> 1, ntB = ntA + 4;
        f32x4 w0 = MFMA(afrag(WB2, 40, mt * 16, 0), afrag(VT, 40, ntA * 16, 0), Z);
        f32x4 w1 = MFMA(afrag(WB2, 40, mt * 16, 0), afrag(VT, 40, ntB * 16, 0), Z);
#pragma unroll
        for (int r = 0; r < 4; ++r) {
            int row = mt * 16 + quad * 4 + r;
            NF[row * 264 + 128 + ntA * 16 + l16] = f2bf(w0[r] * invN);
            NF[row * 264 + 128 + ntB * 16 + l16] = f2bf(w1[r] * invN);
        }
    }
    __syncthreads();

    // ---- P7: F = NF @ Wf1 (K=256) -> ws.F ----
    {
        int mt = wv & 1, nt = wv >> 1;      // 2x4 tiles of 32x64
        f32x4 f = Z;
#pragma unroll
        for (int kt = 0; kt < 8; ++kt)
            f = MFMA(afrag(NF, 264, mt * 16, kt), bfrag_pk(pk + PK_WF1, 4, kt, nt), f);
        float* Fp = ws + WS_F + (size_t)b * 2048;
#pragma unroll
        for (int r = 0; r < 4; ++r)
            Fp[(mt * 16 + quad * 4 + r) * 64 + nt * 16 + l16] = f[r];
    }
}

// ---------------------------------------------------------------------------
// Kernel B: value[b,a,i,:] = lrelu(F[a] + (weight[a,i]/N)*G[i]) @ Wf2  (fp32)
// ---------------------------------------------------------------------------
__global__ __launch_bounds__(256) void critic_B(
    const float* __restrict__ ws, const float* __restrict__ Wf2,
    float* __restrict__ out)
{
    int blk = blockIdx.x;
    int b = blk >> 2, ch = blk & 3;
    int i = threadIdx.x & 31;
    int a = ch * 8 + (threadIdx.x >> 5);
    float w = out[W_OFF + (size_t)b * 1024 + a * 32 + i] * (1.0f / 32.0f);
    const float* F = ws + WS_F + (size_t)b * 2048 + a * 64;
    const float* G = ws + WS_G + (size_t)b * 2048 + i * 64;
    const float4* W2 = (const float4*)Wf2;
    float4 acc[8];
#pragma unroll
    for (int o = 0; o < 8; ++o) acc[o] = make_float4(0.f, 0.f, 0.f, 0.f);
#pragma unroll 8
    for (int d = 0; d < 64; ++d) {
        float z = fmaf(w, G[d], F[d]);
        float h = fmaxf(z, 0.01f * z);
#pragma unroll
        for (int o = 0; o < 8; ++o) {
            float4 ww = W2[d * 8 + o];
            acc[o].x = fmaf(h, ww.x, acc[o].x);
            acc[o].y = fmaf(h, ww.y, acc[o].y);
            acc[o].z = fmaf(h, ww.z, acc[o].z);
            acc[o].w = fmaf(h, ww.w, acc[o].w);
        }
    }
    float4* op4 = (float4*)(out + (size_t)b * 32768 + a * 1024 + i * 32);
#pragma unroll
    for (int o = 0; o < 8; ++o) op4[o] = acc[o];
}

// ---------------------------------------------------------------------------
extern "C" void kernel_launch(void* const* d_in, const int* in_sizes, int n_in,
                              void* d_out, int out_size, void* d_ws, size_t ws_size,
                              hipStream_t stream)
{
    const float* states    = (const float*)d_in[0];
    const float* policies  = (const float*)d_in[1];
    const float* actions   = (const float*)d_in[2];
    const float* states_p  = (const float*)d_in[3];
    const float* actions_p = (const float*)d_in[4];
    const float* Wk        = (const float*)d_in[5];
    const float* Wq        = (const float*)d_in[6];
    const float* Wv        = (const float*)d_in[7];
    const float* Wkp       = (const float*)d_in[8];
    const float* Wqp       = (const float*)d_in[9];
    const float* Wvp       = (const float*)d_in[10];
    const float* Wf1       = (const float*)d_in[11];
    const float* Wf2       = (const float*)d_in[12];
    float* out = (float*)d_out;
    float* ws  = (float*)d_ws;
    unsigned short* pk = (unsigned short*)d_ws;

    pack_weights<<<40, 256, 0, stream>>>(Wq, Wk, Wv, Wkp, Wqp, Wvp, Wf1, pk);
    critic_A<<<256, 512, 0, stream>>>(states, policies, actions,
                                      states_p, actions_p, pk, ws, out);
    critic_B<<<1024, 256, 0, stream>>>(ws, Wf2, out);
}

// Round 4
// 137.583 us; speedup vs baseline: 1.7823x; 1.2353x over previous
//
#include <hip/hip_runtime.h>
#include <math.h>

// Shapes: B=256, N=P=32, OBS=96, ACT=32, DIN=DOUT=128, DF1=64, DF2=32
#define VAL_SZ  (256*32*32*32)
#define W_OFF   VAL_SZ
#define WP_OFF  (VAL_SZ + 256*32*32)

// ws holds only packed bf16 weights (163840 B)
#define PK_WV   0            // ushort offsets
#define PK_WVP  16384
#define PK_MQ   32768
#define PK_MP   49152
#define PK_WF1  65536        // 256x64 packed (kt 0..7, nt 0..3)

typedef short  bf16x8 __attribute__((ext_vector_type(8)));
typedef float  f32x4  __attribute__((ext_vector_type(4)));

#define MFMA(a, b, c) __builtin_amdgcn_mfma_f32_16x16x32_bf16(a, b, c, 0, 0, 0)

static __device__ __forceinline__ unsigned short f2bf(float f) {
    union { float f; unsigned u; } v; v.f = f;
    unsigned r = (v.u + 0x7FFF + ((v.u >> 16) & 1)) >> 16;
    return (unsigned short)r;
}

// A-frag / row-read B-frag from row-major bf16 LDS (stride in ushorts, mult of 8)
static __device__ __forceinline__ bf16x8 afrag(const unsigned short* Mb, int stride,
                                               int row0, int kt) {
    int lane = threadIdx.x & 63;
    return *(const bf16x8*)(Mb + (row0 + (lane & 15)) * stride + kt * 32 + (lane >> 4) * 8);
}

// B-frag from packed global weights
static __device__ __forceinline__ bf16x8 bfrag_pk(const unsigned short* base, int NT,
                                                  int kt, int nt) {
    int lane = threadIdx.x & 63;
    return *(const bf16x8*)(base + (((kt * NT + nt) * 64) + lane) * 8);
}

// ---------------------------------------------------------------------------
// Kernel 0: pack weights to bf16 B-fragment order.
// Blocks 0..23   : Wv / Wvp / Wf1 vector packing (6144 threads)
// Blocks 24..151 : Mq=(Wq@Wk^T)*s, Mp=(Wqp@Wkp^T)*s — ONE ELEMENT PER THREAD
//                  (32768 threads) to stay latency-tolerant.
// Fragment element: B[kt*32 + quad*8 + j][nt*16 + l16] at
//                  pk[((kt*NT+nt)*64 + quad*16+l16)*8 + j]
// ---------------------------------------------------------------------------
__global__ __launch_bounds__(256) void pack_weights(
    const float* __restrict__ Wq, const float* __restrict__ Wk,
    const float* __restrict__ Wv, const float* __restrict__ Wkp,
    const float* __restrict__ Wqp, const float* __restrict__ Wvp,
    const float* __restrict__ Wf1, unsigned short* __restrict__ pk)
{
    const float scale = 0.08838834764831845f;     // 1/sqrt(128)
    if (blockIdx.x < 24) {
        int pid = blockIdx.x * 256 + threadIdx.x;  // 0..6143
        int sub = pid >> 11;                       // 0:Wv 1:Wvp 2:Wf1
        int r = pid & 2047;
        int lane = r & 63;
        int l16 = lane & 15, quad = lane >> 4;
        union { unsigned short u[8]; bf16x8 v; } o;
        if (sub < 2) {                             // 128x128, NT=8
            const float* W = (sub == 0) ? Wv : Wvp;
            int ktnt = r >> 6;
            int n = (ktnt & 7) * 16 + l16;
            int kb = (ktnt >> 3) * 32 + quad * 8;
#pragma unroll
            for (int j = 0; j < 8; ++j) o.u[j] = f2bf(W[(kb + j) * 128 + n]);
            *(bf16x8*)(pk + ((sub == 0) ? PK_WV : PK_WVP) + (ktnt * 64 + lane) * 8) = o.v;
        } else {                                   // Wf1 256x64, NT=4
            int ktnt = r >> 6;
            int n = (ktnt & 3) * 16 + l16;
            int kb = (ktnt >> 2) * 32 + quad * 8;
#pragma unroll
            for (int j = 0; j < 8; ++j) o.u[j] = f2bf(Wf1[(kb + j) * 64 + n]);
            *(bf16x8*)(pk + PK_WF1 + (ktnt * 64 + lane) * 8) = o.v;
        }
    } else {
        int mid = (blockIdx.x - 24) * 256 + threadIdx.x;   // 0..32767
        int mat = mid >> 14;
        int idx = mid & 16383;
        int k = idx >> 7, n = idx & 127;
        const float* A  = (mat == 0) ? Wq : Wqp;
        const float* Bm = (mat == 0) ? Wk : Wkp;
        const float4* a4 = (const float4*)(A + k * 128);
        const float4* b4 = (const float4*)(Bm + n * 128);
        float acc = 0.f;
#pragma unroll 8
        for (int c = 0; c < 32; ++c) {
            float4 x = a4[c], y = b4[c];
            acc = fmaf(x.x, y.x, acc);
            acc = fmaf(x.y, y.y, acc);
            acc = fmaf(x.z, y.z, acc);
            acc = fmaf(x.w, y.w, acc);
        }
        int kt = k >> 5, quad = (k >> 3) & 3, j = k & 7;
        int nt = n >> 4, l16 = n & 15;
        pk[((mat == 0) ? PK_MQ : PK_MP)
           + ((kt * 8 + nt) * 64 + quad * 16 + l16) * 8 + j] = f2bf(acc * scale);
    }
}

// ---------------------------------------------------------------------------
// Kernel A: fully fused per-batch forward (MFMA) + value epilogue.
// grid 256 x 512 threads. LDS 58624 B, regions aliased over phases:
//  OA[32x136 bf16] + T[32x136] (aliased by NF[32x264] from P6a)
//  OP[32x136] : op -> oap
//  VT[128x40 bf16] : vaT -> avpT -> GP[32x67 f32] (epilogue G)
//  SC1/SC2 [32x33 f32] : scores -> fp32 weights (SC1 reused by epilogue)
//  WB1/WB2 [32x40 bf16] : softmax weights for MFMA
//  TP[32x136] : tp -> FP[32x66 f32] (epilogue F)
// ---------------------------------------------------------------------------
__global__ __launch_bounds__(512) void critic_A(
    const float* __restrict__ states, const float* __restrict__ policies,
    const float* __restrict__ actions, const float* __restrict__ states_p,
    const float* __restrict__ actions_p,
    const unsigned short* __restrict__ pk,
    const float* __restrict__ Wf2, float* __restrict__ out)
{
    __shared__ __align__(16) unsigned char SM[58624];
    unsigned short* OA  = (unsigned short*)(SM + 0);       // 32 x 136
    unsigned short* T   = (unsigned short*)(SM + 8704);    // delta -> t
    unsigned short* NF  = (unsigned short*)(SM + 0);       // 32 x 264 (aliases OA+T)
    unsigned short* OP  = (unsigned short*)(SM + 17408);   // op -> oap
    unsigned short* VT  = (unsigned short*)(SM + 26112);   // vaT -> avpT, 128 x 40
    float*          GP  = (float*)(SM + 26112);            // 32 x 67 (epilogue)
    float*          SC1 = (float*)(SM + 36352);            // 32 x 33
    float*          SC2 = (float*)(SM + 40576);
    unsigned short* WB1 = (unsigned short*)(SM + 44800);   // weight bf16 32 x 40
    unsigned short* WB2 = (unsigned short*)(SM + 47360);   // wp bf16
    unsigned short* TP  = (unsigned short*)(SM + 49920);   // tp 32 x 136
    float*          FP  = (float*)(SM + 49920);            // 32 x 66 (epilogue)

    const int tid = threadIdx.x;
    const int b = blockIdx.x;
    const int lane = tid & 63, wv = tid >> 6;
    const int l16 = lane & 15, quad = lane >> 4;
    const float invN = 1.0f / 32.0f;
    const f32x4 Z = {0.f, 0.f, 0.f, 0.f};

    // ---- P0: load oa, op -> bf16 LDS ----
    {
        const float* st = states   + (size_t)b * 3072;
        const float* ac = actions  + (size_t)b * 1024;
        const float* po = policies + (size_t)b * 1024;
#pragma unroll
        for (int k = 0; k < 8; ++k) {
            int idx = tid + k * 512;
            int n = idx >> 7, d = idx & 127;
            float sv, pv;
            if (d < 96) { sv = st[n * 96 + d]; pv = sv; }
            else        { sv = ac[n * 32 + d - 96]; pv = po[n * 32 + d - 96]; }
            OA[n * 136 + d] = f2bf(sv);
            OP[n * 136 + d] = f2bf(pv);
        }
    }
    __syncthreads();

    // ---- P1: va = tanh(oa@Wv) -> vaT; delta = tanh(op@Wv) - va -> T ----
    {
        int mt = wv & 1, ntA = wv >> 1, ntB = ntA + 4;
        f32x4 va0 = Z, va1 = Z, vp0 = Z, vp1 = Z;
#pragma unroll
        for (int kt = 0; kt < 4; ++kt) {
            bf16x8 aA = afrag(OA, 136, mt * 16, kt);
            bf16x8 aP = afrag(OP, 136, mt * 16, kt);
            bf16x8 b0 = bfrag_pk(pk + PK_WV, 8, kt, ntA);
            bf16x8 b1 = bfrag_pk(pk + PK_WV, 8, kt, ntB);
            va0 = MFMA(aA, b0, va0); va1 = MFMA(aA, b1, va1);
            vp0 = MFMA(aP, b0, vp0); vp1 = MFMA(aP, b1, vp1);
        }
#pragma unroll
        for (int r = 0; r < 4; ++r) {
            int row = mt * 16 + quad * 4 + r;
            float tva0 = tanhf(va0[r]), tvp0 = tanhf(vp0[r]);
            float tva1 = tanhf(va1[r]), tvp1 = tanhf(vp1[r]);
            VT[(ntA * 16 + l16) * 40 + row] = f2bf(tva0);
            VT[(ntB * 16 + l16) * 40 + row] = f2bf(tva1);
            T[row * 136 + ntA * 16 + l16] = f2bf(tvp0 - tva0);
            T[row * 136 + ntB * 16 + l16] = f2bf(tvp1 - tva1);
        }
    }
    __syncthreads();

    // ---- P2: G = delta @ Wf1_top -> REGISTERS (parked to LDS in P7) ----
    f32x4 gReg;
    int gmt, gnt;
    {
        gmt = wv & 1; gnt = wv >> 1;        // 2x4 tiles of 32x64
        f32x4 g = Z;
#pragma unroll
        for (int kt = 0; kt < 4; ++kt)
            g = MFMA(afrag(T, 136, gmt * 16, kt), bfrag_pk(pk + PK_WF1, 4, kt, gnt), g);
        gReg = g;

        const float* st = states_p  + (size_t)b * 3072;
        const float* ac = actions_p + (size_t)b * 1024;
#pragma unroll
        for (int k = 0; k < 8; ++k) {
            int idx = tid + k * 512;
            int n = idx >> 7, d = idx & 127;
            OP[n * 136 + d] = f2bf((d < 96) ? st[n * 96 + d] : ac[n * 32 + d - 96]);
        }
    }
    __syncthreads();

    // ---- P3: t = oa@Mq -> T (waves 0-3); tp = oa@Mp -> TP (waves 4-7) ----
    {
        int half = wv >> 2;
        int w4 = wv & 3;
        int mt = w4 & 1, ntb = w4 >> 1;
        const unsigned short* pkM = pk + (half ? PK_MP : PK_MQ);
        unsigned short* outT = half ? TP : T;
        bf16x8 afr[4];
#pragma unroll
        for (int kt = 0; kt < 4; ++kt) afr[kt] = afrag(OA, 136, mt * 16, kt);
#pragma unroll
        for (int t4 = 0; t4 < 4; ++t4) {
            int nt = ntb + t4 * 2;
            f32x4 acc = Z;
#pragma unroll
            for (int kt = 0; kt < 4; ++kt)
                acc = MFMA(afr[kt], bfrag_pk(pkM, 8, kt, nt), acc);
#pragma unroll
            for (int r = 0; r < 4; ++r)
                outT[(mt * 16 + quad * 4 + r) * 136 + nt * 16 + l16] = f2bf(acc[r]);
        }
    }
    __syncthreads();

    // ---- P4: scores -> SC1; scores_p -> SC2 ----
    {
        int half = wv >> 2;
        int w4 = wv & 3;
        int mt = w4 & 1, nt = w4 >> 1;
        const unsigned short* Am = half ? TP : T;
        const unsigned short* Bm = half ? OP : OA;
        float* SC = half ? SC2 : SC1;
        f32x4 acc = Z;
#pragma unroll
        for (int kt = 0; kt < 4; ++kt)
            acc = MFMA(afrag(Am, 136, mt * 16, kt), afrag(Bm, 136, nt * 16, kt), acc);
#pragma unroll
        for (int r = 0; r < 4; ++r)
            SC[(mt * 16 + quad * 4 + r) * 33 + nt * 16 + l16] = acc[r];
    }
    __syncthreads();

    // ---- P5: softmaxes; export fp32; stash bf16 + fp32(SC1) copies ----
    {
        int j = tid & 31, ab = tid >> 5;       // weight: softmax over j per a
#pragma unroll
        for (int rep = 0; rep < 2; ++rep) {
            int a = ab + rep * 16;
            float x = SC1[j * 33 + a];
            float m = x;
#pragma unroll
            for (int msk = 16; msk >= 1; msk >>= 1) m = fmaxf(m, __shfl_xor(m, msk));
            float e = __expf(x - m);
            float s = e;
#pragma unroll
            for (int msk = 16; msk >= 1; msk >>= 1) s += __shfl_xor(s, msk);
            float w = e / s;
            out[W_OFF + (size_t)b * 1024 + a * 32 + j] = w;
            WB1[a * 40 + j] = f2bf(w);
            SC1[j * 33 + a] = w;               // fp32 weight[a,j] for epilogue
        }
        int n = tid & 31, pb = tid >> 5;       // wp: softmax over n per p
#pragma unroll
        for (int rep = 0; rep < 2; ++rep) {
            int p = pb + rep * 16;
            float x = SC2[n * 33 + p];
            float m = x;
#pragma unroll
            for (int msk = 16; msk >= 1; msk >>= 1) m = fmaxf(m, __shfl_xor(m, msk));
            float e = __expf(x - m);
            float s = e;
#pragma unroll
            for (int msk = 16; msk >= 1; msk >>= 1) s += __shfl_xor(s, msk);
            float w = e / s;
            out[WP_OFF + (size_t)b * 1024 + n * 32 + p] = w;
            WB2[n * 40 + p] = f2bf(w);
        }
    }
    __syncthreads();

    // ---- P6a: S_acc = weight@va -> NF[:,0:128]*invN ; avp MFMA into regs ----
    f32x4 av0 = Z, av1 = Z;
    {
        int mt = wv & 1, ntA = wv >> 1, ntB = ntA + 4;
        f32x4 s0 = MFMA(afrag(WB1, 40, mt * 16, 0), afrag(VT, 40, ntA * 16, 0), Z);
        f32x4 s1 = MFMA(afrag(WB1, 40, mt * 16, 0), afrag(VT, 40, ntB * 16, 0), Z);
#pragma unroll
        for (int kt = 0; kt < 4; ++kt) {
            bf16x8 a = afrag(OP, 136, mt * 16, kt);
            av0 = MFMA(a, bfrag_pk(pk + PK_WVP, 8, kt, ntA), av0);
            av1 = MFMA(a, bfrag_pk(pk + PK_WVP, 8, kt, ntB), av1);
        }
#pragma unroll
        for (int r = 0; r < 4; ++r) {
            int row = mt * 16 + quad * 4 + r;
            NF[row * 264 + ntA * 16 + l16] = f2bf(s0[r] * invN);
            NF[row * 264 + ntB * 16 + l16] = f2bf(s1[r] * invN);
        }
    }
    __syncthreads();

    // ---- P6b: avpT -> VT (vaT dead) ----
    {
        int mt = wv & 1, ntA = wv >> 1, ntB = ntA + 4;
#pragma unroll
        for (int r = 0; r < 4; ++r) {
            int row = mt * 16 + quad * 4 + r;        // p index
            VT[(ntA * 16 + l16) * 40 + row] = f2bf(tanhf(av0[r]));
            VT[(ntB * 16 + l16) * 40 + row] = f2bf(tanhf(av1[r]));
        }
    }
    __syncthreads();

    // ---- P6c: wavp = wp@avp -> NF[:,128:256]*invN ----
    {
        int mt = wv & 1, ntA = wv >> 1, ntB = ntA + 4;
        f32x4 w0 = MFMA(afrag(WB2, 40, mt * 16, 0), afrag(VT, 40, ntA * 16, 0), Z);
        f32x4 w1 = MFMA(afrag(WB2, 40, mt * 16, 0), afrag(VT, 40, ntB * 16, 0), Z);
#pragma unroll
        for (int r = 0; r < 4; ++r) {
            int row = mt * 16 + quad * 4 + r;
            NF[row * 264 + 128 + ntA * 16 + l16] = f2bf(w0[r] * invN);
            NF[row * 264 + 128 + ntB * 16 + l16] = f2bf(w1[r] * invN);
        }
    }
    __syncthreads();

    // ---- P7: F = NF @ Wf1 (K=256) -> FP (LDS); park G regs -> GP (LDS) ----
    {
        int mt = wv & 1, nt = wv >> 1;
        f32x4 f = Z;
#pragma unroll
        for (int kt = 0; kt < 8; ++kt)
            f = MFMA(afrag(NF, 264, mt * 16, kt), bfrag_pk(pk + PK_WF1, 4, kt, nt), f);
#pragma unroll
        for (int r = 0; r < 4; ++r) {
            FP[(mt * 16 + quad * 4 + r) * 66 + nt * 16 + l16] = f[r];
            GP[(gmt * 16 + quad * 4 + r) * 67 + gnt * 16 + l16] = gReg[r];
        }
    }
    __syncthreads();

    // ---- P8 (epilogue): value[b,a,i,:] = lrelu(F[a] + (w[a,i]/N)*G[i]) @ Wf2
    {
        const float4* W2 = (const float4*)Wf2;   // lane-uniform -> scalar loads
#pragma unroll
        for (int k2 = 0; k2 < 2; ++k2) {
            int pair = tid + k2 * 512;           // 0..1023
            int a = pair >> 5, i = pair & 31;
            float w = SC1[i * 33 + a] * invN;    // fp32 weight[a,i]
            const float* Fa = FP + a * 66;
            const float* Gi = GP + i * 67;
            float4 acc[8];
#pragma unroll
            for (int o = 0; o < 8; ++o) acc[o] = make_float4(0.f, 0.f, 0.f, 0.f);
#pragma unroll 8
            for (int d = 0; d < 64; ++d) {
                float z = fmaf(w, Gi[d], Fa[d]);
                float h = fmaxf(z, 0.01f * z);
#pragma unroll
                for (int o = 0; o < 8; ++o) {
                    float4 ww = W2[d * 8 + o];
                    acc[o].x = fmaf(h, ww.x, acc[o].x);
                    acc[o].y = fmaf(h, ww.y, acc[o].y);
                    acc[o].z = fmaf(h, ww.z, acc[o].z);
                    acc[o].w = fmaf(h, ww.w, acc[o].w);
                }
            }
            float4* op4 = (float4*)(out + (size_t)b * 32768 + (size_t)pair * 32);
#pragma unroll
            for (int o = 0; o < 8; ++o) op4[o] = acc[o];
        }
    }
}

// ---------------------------------------------------------------------------
extern "C" void kernel_launch(void* const* d_in, const int* in_sizes, int n_in,
                              void* d_out, int out_size, void* d_ws, size_t ws_size,
                              hipStream_t stream)
{
    const float* states    = (const float*)d_in[0];
    const float* policies  = (const float*)d_in[1];
    const float* actions   = (const float*)d_in[2];
    const float* states_p  = (const float*)d_in[3];
    const float* actions_p = (const float*)d_in[4];
    const float* Wk        = (const float*)d_in[5];
    const float* Wq        = (const float*)d_in[6];
    const float* Wv        = (const float*)d_in[7];
    const float* Wkp       = (const float*)d_in[8];
    const float* Wqp       = (const float*)d_in[9];
    const float* Wvp       = (const float*)d_in[10];
    const float* Wf1       = (const float*)d_in[11];
    const float* Wf2       = (const float*)d_in[12];
    float* out = (float*)d_out;
    unsigned short* pk = (unsigned short*)d_ws;

    pack_weights<<<152, 256, 0, stream>>>(Wq, Wk, Wv, Wkp, Wqp, Wvp, Wf1, pk);
    critic_A<<<256, 512, 0, stream>>>(states, policies, actions,
                                      states_p, actions_p, pk, Wf2, out);
}

// Round 5
// 112.274 us; speedup vs baseline: 2.1841x; 1.2254x over previous
//
#include <hip/hip_runtime.h>
#include <math.h>

// Shapes: B=256, N=P=32, OBS=96, ACT=32, DIN=DOUT=128, DF1=64, DF2=32
#define VAL_SZ  (256*32*32*32)
#define W_OFF   VAL_SZ
#define WP_OFF  (VAL_SZ + 256*32*32)

// packed bf16 weights in ws (ushort offsets)
#define PK_WV   0
#define PK_WVP  16384
#define PK_MQ   32768
#define PK_MP   49152
#define PK_WF1  65536        // 256x64 (kt 0..7, nt 0..3)
#define PK_WF2  81920        // 64x32  (kt 0..1, nt 0..1)

typedef short  bf16x8 __attribute__((ext_vector_type(8)));
typedef float  f32x4  __attribute__((ext_vector_type(4)));

#define MFMA(a, b, c) __builtin_amdgcn_mfma_f32_16x16x32_bf16(a, b, c, 0, 0, 0)

static __device__ __forceinline__ unsigned short f2bf(float f) {
    union { float f; unsigned u; } v; v.f = f;
    unsigned r = (v.u + 0x7FFF + ((v.u >> 16) & 1)) >> 16;
    return (unsigned short)r;
}

static __device__ __forceinline__ float fast_tanh(float x) {
    x = fminf(fmaxf(x, -12.0f), 12.0f);
    float e = __expf(2.0f * x);
    return (e - 1.0f) / (e + 1.0f);
}

// A-frag / row-read B-frag from row-major bf16 LDS
static __device__ __forceinline__ bf16x8 afrag(const unsigned short* Mb, int stride,
                                               int row0, int kt) {
    int lane = threadIdx.x & 63;
    return *(const bf16x8*)(Mb + (row0 + (lane & 15)) * stride + kt * 32 + (lane >> 4) * 8);
}

// B-frag from packed global weights
static __device__ __forceinline__ bf16x8 bfrag_pk(const unsigned short* base, int NT,
                                                  int kt, int nt) {
    int lane = threadIdx.x & 63;
    return *(const bf16x8*)(base + (((kt * NT + nt) * 64) + lane) * 8);
}

// ---------------------------------------------------------------------------
// Kernel 0: pack weights to bf16 B-fragment order.
// Blocks 0..23: Wv/Wvp/Wf1. Block 24: Wf2. Blocks 25..152: Mq/Mp (1 elem/thr).
// ---------------------------------------------------------------------------
__global__ __launch_bounds__(256) void pack_weights(
    const float* __restrict__ Wq, const float* __restrict__ Wk,
    const float* __restrict__ Wv, const float* __restrict__ Wkp,
    const float* __restrict__ Wqp, const float* __restrict__ Wvp,
    const float* __restrict__ Wf1, const float* __restrict__ Wf2,
    unsigned short* __restrict__ pk)
{
    const float scale = 0.08838834764831845f;     // 1/sqrt(128)
    if (blockIdx.x < 24) {
        int pid = blockIdx.x * 256 + threadIdx.x;  // 0..6143
        int sub = pid >> 11;                       // 0:Wv 1:Wvp 2:Wf1
        int r = pid & 2047;
        int lane = r & 63;
        int l16 = lane & 15, quad = lane >> 4;
        union { unsigned short u[8]; bf16x8 v; } o;
        if (sub < 2) {                             // 128x128, NT=8
            const float* W = (sub == 0) ? Wv : Wvp;
            int ktnt = r >> 6;
            int n = (ktnt & 7) * 16 + l16;
            int kb = (ktnt >> 3) * 32 + quad * 8;
#pragma unroll
            for (int j = 0; j < 8; ++j) o.u[j] = f2bf(W[(kb + j) * 128 + n]);
            *(bf16x8*)(pk + ((sub == 0) ? PK_WV : PK_WVP) + (ktnt * 64 + lane) * 8) = o.v;
        } else {                                   // Wf1 256x64, NT=4
            int ktnt = r >> 6;
            int n = (ktnt & 3) * 16 + l16;
            int kb = (ktnt >> 2) * 32 + quad * 8;
#pragma unroll
            for (int j = 0; j < 8; ++j) o.u[j] = f2bf(Wf1[(kb + j) * 64 + n]);
            *(bf16x8*)(pk + PK_WF1 + (ktnt * 64 + lane) * 8) = o.v;
        }
    } else if (blockIdx.x == 24) {                 // Wf2 64x32, NT=2
        int r = threadIdx.x;                       // 0..255
        int lane = r & 63;
        int l16 = lane & 15, quad = lane >> 4;
        int ktnt = r >> 6;                         // 0..3
        int n = (ktnt & 1) * 16 + l16;
        int kb = (ktnt >> 1) * 32 + quad * 8;
        union { unsigned short u[8]; bf16x8 v; } o;
#pragma unroll
        for (int j = 0; j < 8; ++j) o.u[j] = f2bf(Wf2[(kb + j) * 32 + n]);
        *(bf16x8*)(pk + PK_WF2 + (ktnt * 64 + lane) * 8) = o.v;
    } else {
        int mid = (blockIdx.x - 25) * 256 + threadIdx.x;   // 0..32767
        int mat = mid >> 14;
        int idx = mid & 16383;
        int k = idx >> 7, n = idx & 127;
        const float* A  = (mat == 0) ? Wq : Wqp;
        const float* Bm = (mat == 0) ? Wk : Wkp;
        const float4* a4 = (const float4*)(A + k * 128);
        const float4* b4 = (const float4*)(Bm + n * 128);
        float acc = 0.f;
#pragma unroll 8
        for (int c = 0; c < 32; ++c) {
            float4 x = a4[c], y = b4[c];
            acc = fmaf(x.x, y.x, acc);
            acc = fmaf(x.y, y.y, acc);
            acc = fmaf(x.z, y.z, acc);
            acc = fmaf(x.w, y.w, acc);
        }
        int kt = k >> 5, quad = (k >> 3) & 3, j = k & 7;
        int nt = n >> 4, l16 = n & 15;
        pk[((mat == 0) ? PK_MQ : PK_MP)
           + ((kt * 8 + nt) * 64 + quad * 16 + l16) * 8 + j] = f2bf(acc * scale);
    }
}

// ---------------------------------------------------------------------------
// Kernel A: fused per-batch forward. grid 256 x 1024 threads (16 waves).
// Wave-specialized phases, 7 barriers. LDS 63744 B:
//  [0,17408)     OA | OP(op->oap)        -> NF[32x264 bf16] (phase E..G)
//  [17408,27648) VT vaT[128x40]
//  [27648,37888) TD delta[32x136] -> avpT[128x40] -> FP[32x66 f32]
//  [37888,46592) TL t[32x136]     -> WB1/WB2 bf16 [32x40]
//  [46592,55296) TPL tp[32x136]   -> GP[32x67 f32]
//  [55296,59520) SC1 [32x33 f32] (scores -> fp32 weight)
//  [59520,63744) SC2 [32x33 f32]
// ---------------------------------------------------------------------------
__global__ __launch_bounds__(1024) void critic_A(
    const float* __restrict__ states, const float* __restrict__ policies,
    const float* __restrict__ actions, const float* __restrict__ states_p,
    const float* __restrict__ actions_p,
    const unsigned short* __restrict__ pk, float* __restrict__ out)
{
    __shared__ __align__(16) unsigned char SM[63744];
    unsigned short* OA  = (unsigned short*)(SM + 0);       // 32 x 136
    unsigned short* OP  = (unsigned short*)(SM + 8704);    // op -> oap
    unsigned short* NF  = (unsigned short*)(SM + 0);       // 32 x 264
    unsigned short* VT  = (unsigned short*)(SM + 17408);   // vaT 128 x 40
    unsigned short* TD  = (unsigned short*)(SM + 27648);   // delta -> avpT
    float*          FP  = (float*)(SM + 27648);            // F 32 x 66
    unsigned short* TL  = (unsigned short*)(SM + 37888);   // t 32 x 136
    unsigned short* WB1 = (unsigned short*)(SM + 37888);   // weight bf16 32x40
    unsigned short* WB2 = (unsigned short*)(SM + 40448);   // wp bf16 32x40
    unsigned short* TPL = (unsigned short*)(SM + 46592);   // tp 32 x 136
    float*          GP  = (float*)(SM + 46592);            // G 32 x 67
    float*          SC1 = (float*)(SM + 55296);            // 32 x 33
    float*          SC2 = (float*)(SM + 59520);

    const int tid = threadIdx.x;
    const int b = blockIdx.x;
    const int lane = tid & 63, wv = tid >> 6;              // wv 0..15
    const int l16 = lane & 15, quad = lane >> 4;
    const float invN = 1.0f / 32.0f;
    const f32x4 Z = {0.f, 0.f, 0.f, 0.f};

    // ---- P0: load oa -> OA, op -> OP (bf16) ----
    {
        const float* st = states   + (size_t)b * 3072;
        const float* ac = actions  + (size_t)b * 1024;
        const float* po = policies + (size_t)b * 1024;
#pragma unroll
        for (int k = 0; k < 4; ++k) {
            int idx = tid + k * 1024;
            int n = idx >> 7, d = idx & 127;
            float sv, pv;
            if (d < 96) { sv = st[n * 96 + d]; pv = sv; }
            else        { sv = ac[n * 32 + d - 96]; pv = po[n * 32 + d - 96]; }
            OA[n * 136 + d] = f2bf(sv);
            OP[n * 136 + d] = f2bf(pv);
        }
    }
    __syncthreads();

    // ---- Phase A: waves 0-7: va->VT, delta->TD ; waves 8-15: t->TL, tp->TPL
    if (wv < 8) {
        int mt = wv & 1, ntA = wv >> 1, ntB = ntA + 4;
        f32x4 va0 = Z, va1 = Z, vp0 = Z, vp1 = Z;
#pragma unroll
        for (int kt = 0; kt < 4; ++kt) {
            bf16x8 aA = afrag(OA, 136, mt * 16, kt);
            bf16x8 aP = afrag(OP, 136, mt * 16, kt);
            bf16x8 b0 = bfrag_pk(pk + PK_WV, 8, kt, ntA);
            bf16x8 b1 = bfrag_pk(pk + PK_WV, 8, kt, ntB);
            va0 = MFMA(aA, b0, va0); va1 = MFMA(aA, b1, va1);
            vp0 = MFMA(aP, b0, vp0); vp1 = MFMA(aP, b1, vp1);
        }
#pragma unroll
        for (int r = 0; r < 4; ++r) {
            int row = mt * 16 + quad * 4 + r;
            float tva0 = fast_tanh(va0[r]), tvp0 = fast_tanh(vp0[r]);
            float tva1 = fast_tanh(va1[r]), tvp1 = fast_tanh(vp1[r]);
            VT[(ntA * 16 + l16) * 40 + row] = f2bf(tva0);
            VT[(ntB * 16 + l16) * 40 + row] = f2bf(tva1);
            TD[row * 136 + ntA * 16 + l16] = f2bf(tvp0 - tva0);
            TD[row * 136 + ntB * 16 + l16] = f2bf(tvp1 - tva1);
        }
    } else {
        int q = wv - 8;
        int q4 = q & 3;
        int mt = q4 & 1, ntb = q4 >> 1;
        const unsigned short* pkM = pk + ((q < 4) ? PK_MQ : PK_MP);
        unsigned short* outT = (q < 4) ? TL : TPL;
        bf16x8 afr[4];
#pragma unroll
        for (int kt = 0; kt < 4; ++kt) afr[kt] = afrag(OA, 136, mt * 16, kt);
#pragma unroll
        for (int t4 = 0; t4 < 4; ++t4) {
            int nt = ntb + t4 * 2;
            f32x4 acc = Z;
#pragma unroll
            for (int kt = 0; kt < 4; ++kt)
                acc = MFMA(afr[kt], bfrag_pk(pkM, 8, kt, nt), acc);
#pragma unroll
            for (int r = 0; r < 4; ++r)
                outT[(mt * 16 + quad * 4 + r) * 136 + nt * 16 + l16] = f2bf(acc[r]);
        }
    }
    __syncthreads();

    // ---- Phase B: waves 0-7: G = delta@Wf1_top (regs); waves 8-15: oap -> OP
    f32x4 gReg = Z;
    int gmt = 0, gnt = 0;
    if (wv < 8) {
        gmt = wv & 1; gnt = wv >> 1;          // 8 tiles of 32x64
#pragma unroll
        for (int kt = 0; kt < 4; ++kt)
            gReg = MFMA(afrag(TD, 136, gmt * 16, kt), bfrag_pk(pk + PK_WF1, 4, kt, gnt), gReg);
    } else {
        const float* st = states_p  + (size_t)b * 3072;
        const float* ac = actions_p + (size_t)b * 1024;
        int t512 = tid - 512;
#pragma unroll
        for (int k = 0; k < 8; ++k) {
            int idx = t512 + k * 512;
            int n = idx >> 7, d = idx & 127;
            OP[n * 136 + d] = f2bf((d < 96) ? st[n * 96 + d] : ac[n * 32 + d - 96]);
        }
    }
    __syncthreads();

    // ---- Phase C: waves 0-7: scores->SC1 / scores_p->SC2 ; waves 8-15: avpT->TD
    if (wv < 8) {
        int sp = wv >> 2;                      // 0: scores, 1: scores_p
        int w4 = wv & 3;
        int mt = w4 & 1, nt = w4 >> 1;
        const unsigned short* Am = sp ? TPL : TL;
        const unsigned short* Bm = sp ? OP : OA;
        float* SC = sp ? SC2 : SC1;
        f32x4 acc = Z;
#pragma unroll
        for (int kt = 0; kt < 4; ++kt)
            acc = MFMA(afrag(Am, 136, mt * 16, kt), afrag(Bm, 136, nt * 16, kt), acc);
#pragma unroll
        for (int r = 0; r < 4; ++r)
            SC[(mt * 16 + quad * 4 + r) * 33 + nt * 16 + l16] = acc[r];
    } else {
        int q = wv - 8;
        int mt = q & 1, ntA = q >> 1, ntB = ntA + 4;
        f32x4 a0 = Z, a1 = Z;
#pragma unroll
        for (int kt = 0; kt < 4; ++kt) {
            bf16x8 a = afrag(OP, 136, mt * 16, kt);
            a0 = MFMA(a, bfrag_pk(pk + PK_WVP, 8, kt, ntA), a0);
            a1 = MFMA(a, bfrag_pk(pk + PK_WVP, 8, kt, ntB), a1);
        }
#pragma unroll
        for (int r = 0; r < 4; ++r) {
            int row = mt * 16 + quad * 4 + r;      // p index
            TD[(ntA * 16 + l16) * 40 + row] = f2bf(fast_tanh(a0[r]));
            TD[(ntB * 16 + l16) * 40 + row] = f2bf(fast_tanh(a1[r]));
        }
    }
    __syncthreads();

    // ---- Phase D: softmaxes (1024 threads, one slot each); exports + stashes
    {
        int j = tid & 31, a = (tid >> 5) & 31;     // weight: softmax over j per a
        float x = SC1[j * 33 + a];
        float m = x;
#pragma unroll
        for (int msk = 16; msk >= 1; msk >>= 1) m = fmaxf(m, __shfl_xor(m, msk));
        float e = __expf(x - m);
        float s = e;
#pragma unroll
        for (int msk = 16; msk >= 1; msk >>= 1) s += __shfl_xor(s, msk);
        float w = e / s;
        out[W_OFF + (size_t)b * 1024 + a * 32 + j] = w;
        WB1[a * 40 + j] = f2bf(w);
        SC1[j * 33 + a] = w;                       // fp32 weight[a,j] for epilogue

        int n = tid & 31, p = (tid >> 5) & 31;     // wp: softmax over n per p
        float x2 = SC2[n * 33 + p];
        float m2 = x2;
#pragma unroll
        for (int msk = 16; msk >= 1; msk >>= 1) m2 = fmaxf(m2, __shfl_xor(m2, msk));
        float e2 = __expf(x2 - m2);
        float s2 = e2;
#pragma unroll
        for (int msk = 16; msk >= 1; msk >>= 1) s2 += __shfl_xor(s2, msk);
        float w2 = e2 / s2;
        out[WP_OFF + (size_t)b * 1024 + n * 32 + p] = w2;
        WB2[n * 40 + p] = f2bf(w2);
    }
    __syncthreads();

    // ---- Phase E: S_acc = weight@va, wavp = wp@avp -> NF (bf16, *invN) ----
    {
        int mt = wv & 1, nt = wv >> 1;             // 16 waves: 1 tile each of both
        f32x4 s = MFMA(afrag(WB1, 40, mt * 16, 0), afrag(VT, 40, nt * 16, 0), Z);
        f32x4 wvp = MFMA(afrag(WB2, 40, mt * 16, 0), afrag(TD, 40, nt * 16, 0), Z);
#pragma unroll
        for (int r = 0; r < 4; ++r) {
            int row = mt * 16 + quad * 4 + r;
            NF[row * 264 + nt * 16 + l16]       = f2bf(s[r] * invN);
            NF[row * 264 + 128 + nt * 16 + l16] = f2bf(wvp[r] * invN);
        }
    }
    __syncthreads();

    // ---- Phase G: F = NF@Wf1 (K=256) -> FP; park gReg -> GP ----
    if (wv < 8) {
        int mt = wv & 1, nt = wv >> 1;             // 8 tiles of 32x64
        f32x4 f = Z;
#pragma unroll
        for (int kt = 0; kt < 8; ++kt)
            f = MFMA(afrag(NF, 264, mt * 16, kt), bfrag_pk(pk + PK_WF1, 4, kt, nt), f);
#pragma unroll
        for (int r = 0; r < 4; ++r) {
            FP[(mt * 16 + quad * 4 + r) * 66 + nt * 16 + l16] = f[r];
            GP[(gmt * 16 + quad * 4 + r) * 67 + gnt * 16 + l16] = gReg[r];
        }
    }
    __syncthreads();

    // ---- Epilogue: value tiles via MFMA; h built in-register (A-frag order)
    {
        bf16x8 bw[2][2];
#pragma unroll
        for (int kt = 0; kt < 2; ++kt)
#pragma unroll
            for (int nt = 0; nt < 2; ++nt)
                bw[kt][nt] = bfrag_pk(pk + PK_WF2, 2, kt, nt);

#pragma unroll
        for (int t4 = 0; t4 < 4; ++t4) {
            int tile = wv + t4 * 16;               // 0..63
            int m0 = tile * 16;
            int a = m0 >> 5;
            int i = (m0 & 31) + l16;
            float w = SC1[i * 33 + a] * invN;
            const float* Fa = FP + a * 66;
            const float* Gi = GP + i * 67;
            f32x4 acc0 = Z, acc1 = Z;
#pragma unroll
            for (int kt = 0; kt < 2; ++kt) {
                union { unsigned short u[8]; bf16x8 v; } h;
                int dbase = kt * 32 + quad * 8;
#pragma unroll
                for (int j = 0; j < 8; ++j) {
                    float z = fmaf(w, Gi[dbase + j], Fa[dbase + j]);
                    z = fmaxf(z, 0.01f * z);       // leaky_relu
                    h.u[j] = f2bf(z);
                }
                acc0 = MFMA(h.v, bw[kt][0], acc0);
                acc1 = MFMA(h.v, bw[kt][1], acc1);
            }
            float* base = out + (size_t)b * 32768 + (size_t)m0 * 32;
#pragma unroll
            for (int r = 0; r < 4; ++r) {
                int row = quad * 4 + r;
                base[row * 32 + l16]      = acc0[r];
                base[row * 32 + 16 + l16] = acc1[r];
            }
        }
    }
}

// ---------------------------------------------------------------------------
extern "C" void kernel_launch(void* const* d_in, const int* in_sizes, int n_in,
                              void* d_out, int out_size, void* d_ws, size_t ws_size,
                              hipStream_t stream)
{
    const float* states    = (const float*)d_in[0];
    const float* policies  = (const float*)d_in[1];
    const float* actions   = (const float*)d_in[2];
    const float* states_p  = (const float*)d_in[3];
    const float* actions_p = (const float*)d_in[4];
    const float* Wk        = (const float*)d_in[5];
    const float* Wq        = (const float*)d_in[6];
    const float* Wv        = (const float*)d_in[7];
    const float* Wkp       = (const float*)d_in[8];
    const float* Wqp       = (const float*)d_in[9];
    const float* Wvp       = (const float*)d_in[10];
    const float* Wf1       = (const float*)d_in[11];
    const float* Wf2       = (const float*)d_in[12];
    float* out = (float*)d_out;
    unsigned short* pk = (unsigned short*)d_ws;

    pack_weights<<<153, 256, 0, stream>>>(Wq, Wk, Wv, Wkp, Wqp, Wvp, Wf1, Wf2, pk);
    critic_A<<<256, 1024, 0, stream>>>(states, policies, actions,
                                       states_p, actions_p, pk, out);
}